// Round 3
// baseline (531.905 us; speedup 1.0000x reference)
//
#include <hip/hip_runtime.h>
#include <hip/hip_bf16.h>
#include <stdint.h>

// B=1024, N=16, D=64, H=64, A=64 -> 16384 nodes. All tensors fp32.
#define NNODE 16384
#define TAU_ 0.01f
#define EPSG 1e-10f

// ---- workspace layout (float offsets); total 1,114,112 floats = 4.25 MB ----
#define OFF_WENC 0
#define OFF_BENC 4096
// bf16 hi/lo weight copies (reuse the old f32 Wih/Whh slots)
#define OFF_WIHF_H 4160      // 192x128 bf16 = 24576 ushort = 12288 fl
#define OFF_WIHF_L 16448
#define OFF_WHHF_H 28736     // 192x64 bf16 = 12288 ushort = 6144 fl
#define OFF_BIHF 41024
#define OFF_BHHF 41216
#define OFF_WIHB_H 41408
#define OFF_WIHB_L 53696
#define OFF_WHHB_H 65984
#define OFF_BIHB 78272
#define OFF_BHHB 78464
#define OFF_WHARD 78656
#define OFF_BHARD 78912
#define OFF_WQ 78914
#define OFF_WK 83010
#define OFF_WV 87106
#define OFF_BV 91202
#define OFF_WIHC 91266
#define OFF_WHHC 103554
#define OFF_BIHC 115842
#define OFF_BHHC 116034
#define OFF_WENCT_H 118784   // Wenc^T bf16 hi: 64x64 = 4096 ushort = 2048 fl
#define OFF_WENCT_L 120832
#define OFF_YF 131072
#define OFF_YB (OFF_YF + 491520)
#define WS_FLOATS (OFF_YB + 491520)

typedef float  v4f __attribute__((ext_vector_type(4)));
typedef short  v8s __attribute__((ext_vector_type(8)));

__device__ __forceinline__ float sigf(float x){ return 1.0f/(1.0f + __expf(-x)); }
__device__ __forceinline__ float tanhfast(float x){ return 1.0f - 2.0f/(__expf(2.0f*x)+1.0f); }
__device__ __forceinline__ unsigned short f2bf(float f){
  __hip_bfloat16 h = __float2bfloat16(f);
  return *reinterpret_cast<unsigned short*>(&h);
}
__device__ __forceinline__ float bf2f(unsigned short u){
  union { unsigned int i; float f; } v; v.i = ((unsigned int)u) << 16; return v.f;
}

// ---------------- K0: copy f32 weights still needed as f32 ----------------
struct Prep {
  const float* s[20];
  int n[20];
  int o[20];
};
__global__ void k_prep(Prep p, float* __restrict__ ws){
  int a = blockIdx.y;
  int i = blockIdx.x * blockDim.x + threadIdx.x;
  if (i < p.n[a]) ws[p.o[a] + i] = p.s[a][i];
}

// ---------------- K0b: bf16 hi/lo splits of the MFMA weights ----------------
__global__ void k_prep2(const float* __restrict__ wenc,
                        const float* __restrict__ wihf, const float* __restrict__ wihb,
                        const float* __restrict__ whhf, const float* __restrict__ whhb,
                        float* __restrict__ ws){
  int a = blockIdx.y;
  int i = blockIdx.x * blockDim.x + threadIdx.x;
  if (a == 0){
    if (i < 4096){
      float x = wenc[((i & 63) << 6) | (i >> 6)];   // WencT[l][d] = Wenc[d][l]
      unsigned short h = f2bf(x);
      unsigned short l = f2bf(x - bf2f(h));
      ((unsigned short*)(ws + OFF_WENCT_H))[i] = h;
      ((unsigned short*)(ws + OFF_WENCT_L))[i] = l;
    }
  } else if (a == 1 || a == 2){
    if (i < 24576){
      float x = (a == 1 ? wihf : wihb)[i];
      unsigned short h = f2bf(x);
      unsigned short l = f2bf(x - bf2f(h));
      ((unsigned short*)(ws + (a == 1 ? OFF_WIHF_H : OFF_WIHB_H)))[i] = h;
      ((unsigned short*)(ws + (a == 1 ? OFF_WIHF_L : OFF_WIHB_L)))[i] = l;
    }
  } else {
    if (i < 12288){
      float x = (a == 3 ? whhf : whhb)[i];
      ((unsigned short*)(ws + (a == 3 ? OFF_WHHF_H : OFF_WHHB_H)))[i] = f2bf(x);
    }
  }
}

// ---------------- K1: bidirectional 15-step GRU via bf16 MFMA ---------------
// grid 512 (dir = bid>>8).  512 thr = 8 waves; wave w: lw=w>>2, nw=w&3.
// Setup (h_enc, u2, cb) = split-bf16 MFMA GEMMs.  launch_bounds arg2 is
// BLOCKS/CU (R1 evidence: arg2=4 -> VGPR 64 -> 388MB spill).  2 blocks/CU.
// NEW: distributed y-reducer — a0/a1 accumulated from fp32 hn in regs,
// shfl_xor over q, parity-buffered LDS combine across the lw wave pair.
// Replaces the serial tid<64 reducer (bank-conflicted LDS re-reads).
__global__ __launch_bounds__(512, 2) void k_gru(const float* __restrict__ obs,
                                                float* __restrict__ ws){
  __shared__ float smem[18432];               // 72 KB -> 2 blocks/CU
  float* s_u2 = smem;                         // [j-node][196] rows g*64+l : 12544
  unsigned short* s_obs_h = (unsigned short*)(smem + 12544); // obs/h_enc hi [64][72]
  unsigned short* s_obs_l = s_obs_h + 4608;                  // lo [64][72]
  unsigned short* s_hbu   = (unsigned short*)(smem + 12544); // loop h: 2 x [64][88] (aliases)
  float* s_red = smem + 18176;                // 2 x [64][2] y-partials (parity)

  const int tid = threadIdx.x;
  const int nl  = tid & 63;
  const int grp = __builtin_amdgcn_readfirstlane(tid >> 6);
  const int dir = blockIdx.x >> 8;
  const int base = (blockIdx.x & 255) * 64;
  const int lw = grp >> 2;                    // 0,1 : l-range 32*lw..+32 (loop rows)
  const int nw = grp & 3;                     // node-tile
  const int q  = nl >> 4;                     // quad
  const int i_c = nl & 15;
  const int node = 16*nw + i_c;               // this thread's target node (local)

  // P0: stage obs as bf16 hi/lo, B-frag friendly layout [node][72]
  {
    float4 a = *(const float4*)&obs[base*64 + tid*8];
    float4 b = *(const float4*)&obs[base*64 + tid*8 + 4];
    int nn = tid >> 3, d0 = (tid & 7)*8;
    union { v8s v; unsigned short u[8]; } H, L;
    float xs[8] = {a.x,a.y,a.z,a.w,b.x,b.y,b.z,b.w};
    #pragma unroll
    for (int e = 0; e < 8; e++){
      H.u[e] = f2bf(xs[e]);
      L.u[e] = f2bf(xs[e] - bf2f(H.u[e]));
    }
    *(v8s*)&s_obs_h[nn*72 + d0] = H.v;
    *(v8s*)&s_obs_l[nn*72 + d0] = L.v;
  }
  __syncthreads();

  // P1: h_enc = relu(obs @ Wenc + b_enc) via MFMA.
  const float* benc = ws + OFF_BENC;
  const unsigned short* wtH = (const unsigned short*)(ws + OFF_WENCT_H);
  const unsigned short* wtL = (const unsigned short*)(ws + OFF_WENCT_L);
  v4f dEnc[2];
  {
    v8s obH[2], obL[2];
    #pragma unroll
    for (int kc = 0; kc < 2; kc++){
      int ba = node*72 + kc*32 + q*8;
      obH[kc] = *(const v8s*)&s_obs_h[ba];
      obL[kc] = *(const v8s*)&s_obs_l[ba];
    }
    #pragma unroll
    for (int tt = 0; tt < 2; tt++){
      int lT = 2*lw + tt;
      float4 bi = *(const float4*)&benc[16*lT + 4*q];
      v4f d = (v4f){bi.x, bi.y, bi.z, bi.w};
      #pragma unroll
      for (int kc = 0; kc < 2; kc++){
        int aa = (16*lT + i_c)*64 + kc*32 + q*8;
        v8s aH = *(const v8s*)&wtH[aa];
        v8s aL = *(const v8s*)&wtL[aa];
        d = __builtin_amdgcn_mfma_f32_16x16x32_bf16(aH, obH[kc], d, 0,0,0);
        d = __builtin_amdgcn_mfma_f32_16x16x32_bf16(aH, obL[kc], d, 0,0,0);
        d = __builtin_amdgcn_mfma_f32_16x16x32_bf16(aL, obH[kc], d, 0,0,0);
      }
      dEnc[tt] = d;
    }
  }
  __syncthreads();   // all obs reads done -> safe to overwrite in place
  #pragma unroll
  for (int tt = 0; tt < 2; tt++){
    int lT = 2*lw + tt;
    unsigned short hh[4], ll[4];
    #pragma unroll
    for (int r = 0; r < 4; r++){
      float v = fmaxf(dEnc[tt][r], 0.0f);
      hh[r] = f2bf(v);
      ll[r] = f2bf(v - bf2f(hh[r]));
    }
    int wa = node*72 + 16*lT + 4*q;   // D: col=node, rows 16lT+4q+r (consecutive)
    *(uint2*)&s_obs_h[wa] = make_uint2((unsigned)hh[0] | ((unsigned)hh[1]<<16),
                                       (unsigned)hh[2] | ((unsigned)hh[3]<<16));
    *(uint2*)&s_obs_l[wa] = make_uint2((unsigned)ll[0] | ((unsigned)ll[1]<<16),
                                       (unsigned)ll[2] | ((unsigned)ll[3]<<16));
  }
  __syncthreads();

  const float* bih = ws + (dir ? OFF_BIHB : OFF_BIHF);
  const float* bhh = ws + (dir ? OFF_BHHB : OFF_BHHF);
  const unsigned short* wiH = (const unsigned short*)(ws + (dir ? OFF_WIHB_H : OFF_WIHF_H));
  const unsigned short* wiL = (const unsigned short*)(ws + (dir ? OFF_WIHB_L : OFF_WIHF_L));
  const unsigned short* whH = (const unsigned short*)(ws + (dir ? OFF_WHHB_H : OFF_WHHF_H));

  // shared B-frags: h_enc hi/lo for this wave's node-tile (cols 16nw..)
  v8s hbH[2], hbL[2];
  #pragma unroll
  for (int kc = 0; kc < 2; kc++){
    int ba = node*72 + kc*32 + q*8;
    hbH[kc] = *(const v8s*)&s_obs_h[ba];
    hbL[kc] = *(const v8s*)&s_obs_l[ba];
  }

  // P2a: u2[j][row] = WihR . h_enc[j]  (A = Wih[:,64:128]).  Wave: M-tiles 6lw+m.
  #pragma unroll
  for (int m = 0; m < 6; m++){
    int T = 6*lw + m;
    v4f d = (v4f){0.f,0.f,0.f,0.f};
    #pragma unroll
    for (int kc = 0; kc < 2; kc++){
      int aa = (16*T + i_c)*128 + 64 + kc*32 + q*8;
      v8s aH = *(const v8s*)&wiH[aa];
      v8s aL = *(const v8s*)&wiL[aa];
      d = __builtin_amdgcn_mfma_f32_16x16x32_bf16(aH, hbH[kc], d, 0,0,0);
      d = __builtin_amdgcn_mfma_f32_16x16x32_bf16(aH, hbL[kc], d, 0,0,0);
      d = __builtin_amdgcn_mfma_f32_16x16x32_bf16(aL, hbH[kc], d, 0,0,0);
    }
    *(v4f*)&s_u2[node*196 + 16*T + 4*q] = d;   // rows 16T+4q..+3, col=node
  }

  // P2b: cb = bias + WihL . h_i  -> lands directly in the loop's C-layout.
  v4f cbr[2], cbz[2], cbn[2], bhn4[2];
  #pragma unroll
  for (int g = 0; g < 3; g++){
    #pragma unroll
    for (int t2 = 0; t2 < 2; t2++){
      int row0 = 64*g + 32*lw + 16*t2 + 4*q;
      float4 bi = *(const float4*)&bih[row0];
      v4f d;
      if (g < 2){
        float4 bh = *(const float4*)&bhh[row0];
        d = (v4f){bi.x+bh.x, bi.y+bh.y, bi.z+bh.z, bi.w+bh.w};
      } else {
        d = (v4f){bi.x, bi.y, bi.z, bi.w};
      }
      int T = (64*g + 32*lw + 16*t2) >> 4;
      #pragma unroll
      for (int kc = 0; kc < 2; kc++){
        int aa = (16*T + i_c)*128 + kc*32 + q*8;   // left half of Wih
        v8s aH = *(const v8s*)&wiH[aa];
        v8s aL = *(const v8s*)&wiL[aa];
        d = __builtin_amdgcn_mfma_f32_16x16x32_bf16(aH, hbH[kc], d, 0,0,0);
        d = __builtin_amdgcn_mfma_f32_16x16x32_bf16(aH, hbL[kc], d, 0,0,0);
        d = __builtin_amdgcn_mfma_f32_16x16x32_bf16(aL, hbH[kc], d, 0,0,0);
      }
      if (g == 0) cbr[t2] = d; else if (g == 1) cbz[t2] = d; else cbn[t2] = d;
    }
  }
  #pragma unroll
  for (int t2 = 0; t2 < 2; t2++){
    int row0 = 128 + 32*lw + 16*t2 + 4*q;
    float4 nh = *(const float4*)&bhh[row0];
    bhn4[t2] = (v4f){nh.x, nh.y, nh.z, nh.w};
  }

  // P2c: Whh -> persistent bf16 A-fragments (pre-split, single 16B load each).
  v8s afr[2][2], afz[2][2], afn[2][2];
  #pragma unroll
  for (int t2 = 0; t2 < 2; t2++){
    #pragma unroll
    for (int kc = 0; kc < 2; kc++){
      #pragma unroll
      for (int g = 0; g < 3; g++){
        int row = g*64 + 32*lw + 16*t2 + i_c;
        v8s a = *(const v8s*)&whH[row*64 + kc*32 + q*8];
        if (g == 0) afr[t2][kc] = a; else if (g == 1) afz[t2][kc] = a; else afn[t2][kc] = a;
      }
    }
  }

  // W_hard rows for this thread's 8 l's (regs; avoids per-step LDS re-reads)
  const float* whard = ws + OFF_WHARD + dir*128;
  float wh0[8], wh1[8];
  #pragma unroll
  for (int t2 = 0; t2 < 2; t2++){
    #pragma unroll
    for (int r = 0; r < 4; r++){
      int l = 32*lw + 16*t2 + 4*q + r;
      wh0[t2*4+r] = whard[l*2];
      wh1[t2*4+r] = whard[l*2+1];
    }
  }
  __syncthreads();   // u2 visible; all s_obs reads done; s_hbu (alias) writable

  // P3: 15-step recurrence (h stride 88 ushorts)
  float* yout = ws + (dir ? OFF_YB : OFF_YF);

  float hv[8];
  #pragma unroll
  for (int m = 0; m < 8; m++) hv[m] = 0.0f;

  for (int kk = 0; kk < 15; kk++){
    const int t  = dir ? (14 - kk) : kk;
    const int j  = t + (t >= i_c ? 1 : 0);
    const int jl = 16*nw + j;
    const int rb = kk & 1;            // read buffer (valid for kk>0)
    const int wb = (kk + 1) & 1;      // write buffer

    v8s b0, b1;
    if (kk > 0){
      const unsigned short* rp = s_hbu + rb*5632 + node*88 + q*8;
      b0 = *(const v8s*)(rp);
      b1 = *(const v8s*)(rp + 32);
    }

    float a0p = 0.f, a1p = 0.f;
    #pragma unroll
    for (int t2 = 0; t2 < 2; t2++){
      int l0 = 32*lw + 16*t2 + 4*q;
      v4f dr = cbr[t2], dz = cbz[t2];
      v4f dn = (v4f){0.f,0.f,0.f,0.f};
      if (kk > 0){
        dr = __builtin_amdgcn_mfma_f32_16x16x32_bf16(afr[t2][0], b0, dr, 0,0,0);
        dr = __builtin_amdgcn_mfma_f32_16x16x32_bf16(afr[t2][1], b1, dr, 0,0,0);
        dz = __builtin_amdgcn_mfma_f32_16x16x32_bf16(afz[t2][0], b0, dz, 0,0,0);
        dz = __builtin_amdgcn_mfma_f32_16x16x32_bf16(afz[t2][1], b1, dz, 0,0,0);
        dn = __builtin_amdgcn_mfma_f32_16x16x32_bf16(afn[t2][0], b0, dn, 0,0,0);
        dn = __builtin_amdgcn_mfma_f32_16x16x32_bf16(afn[t2][1], b1, dn, 0,0,0);
      }
      v4f ur = *(const v4f*)&s_u2[jl*196 +       l0];
      v4f uz = *(const v4f*)&s_u2[jl*196 +  64 + l0];
      v4f un = *(const v4f*)&s_u2[jl*196 + 128 + l0];
      float hn[4];
      #pragma unroll
      for (int r = 0; r < 4; r++){
        float rg = sigf(dr[r] + ur[r]);
        float zg = sigf(dz[r] + uz[r]);
        float ng = tanhfast(cbn[t2][r] + un[r] + rg*(bhn4[t2][r] + dn[r]));
        float hnew = (1.0f - zg)*ng + zg*hv[t2*4+r];
        hv[t2*4+r] = hnew;
        hn[r] = hnew;
        a0p += hnew*wh0[t2*4+r];
        a1p += hnew*wh1[t2*4+r];
      }
      unsigned int p0 = (unsigned int)f2bf(hn[0]) | ((unsigned int)f2bf(hn[1]) << 16);
      unsigned int p1 = (unsigned int)f2bf(hn[2]) | ((unsigned int)f2bf(hn[3]) << 16);
      *(uint2*)(s_hbu + wb*5632 + node*88 + l0) = make_uint2(p0, p1);
    }

    // q-reduction (lanes differing in bits 4..5 hold same (node,l-range))
    a0p += __shfl_xor(a0p, 16); a0p += __shfl_xor(a0p, 32);
    a1p += __shfl_xor(a1p, 16); a1p += __shfl_xor(a1p, 32);
    float* sr = s_red + rb*128;            // parity buffer (kk&1)
    if (lw == 0 && q == 0)
      *(float2*)&sr[node*2] = make_float2(a0p, a1p);
    __syncthreads();
    if (lw == 1 && q == 0){
      float2 pp = *(const float2*)&sr[node*2];
      *(float2*)&yout[((base + node)*15 + t)*2] = make_float2(a0p + pp.x, a1p + pp.y);
    }
  }
}

// ---------------- K2: qkv + gumbel + attention + final GRU cell -------------
// NEW: 512 blocks x 32 nodes (two 16-node graphs) instead of 256 x 64.
// 256 thr = 8 grps x 8 a-lanes.  LDS 39.5 KB -> 2 blocks/CU resident
// (was 1 block/CU = 1 wave/SIMD, zero latency hiding).
__global__ __launch_bounds__(256, 2) void k_attn(const float* __restrict__ obs,
                                                 const float* __restrict__ hid,
                                                 const float* __restrict__ gum,
                                                 float* __restrict__ ws,
                                                 float* __restrict__ out){
  __shared__ float smem[10112];          // 39.5 KB
  float* s_k  = smem;                    // 2048  [a][node32]
  float* s_v  = smem + 2048;             // 2048
  float* s_x  = smem + 4096;             // 2176  [node32][68]: obs -> h_enc -> x
  float* s_sp = smem + 6272;             // 3840  score partials
  float* s_h0 = smem;                    // 2176, aliases dead s_k/s_v (late phases)
  const int tid = threadIdx.x;
  const int nl  = tid & 31;              // node local
  const int grp = tid >> 5;              // 0..7 : a-slice grp*8..+8
  const int base = blockIdx.x * 32;
  const int node = base + nl;

  for (int k = tid; k < 2048; k += 256)
    s_x[(k>>6)*68 + (k&63)] = obs[base*64 + k];
  __syncthreads();

  const float* wenc = ws + OFF_WENC; const float* benc = ws + OFF_BENC;
  {
    float he[8];
    #pragma unroll
    for (int il = 0; il < 8; il++) he[il] = benc[grp*8 + il];
    #pragma unroll
    for (int dq = 0; dq < 16; dq++){
      float4 o4 = *(const float4*)&s_x[nl*68 + 4*dq];
      #pragma unroll
      for (int il = 0; il < 8; il++){
        int l = grp*8 + il;
        he[il] += o4.x*wenc[(4*dq+0)*64+l] + o4.y*wenc[(4*dq+1)*64+l]
                + o4.z*wenc[(4*dq+2)*64+l] + o4.w*wenc[(4*dq+3)*64+l];
      }
    }
    __syncthreads();
    #pragma unroll
    for (int il = 0; il < 8; il++) s_x[nl*68 + grp*8 + il] = fmaxf(he[il], 0.0f);
  }
  __syncthreads();

  const float* wq = ws+OFF_WQ; const float* wk = ws+OFF_WK;
  const float* wv = ws+OFF_WV; const float* bv = ws+OFF_BV;
  {
    float ak[8];
    #pragma unroll
    for (int il = 0; il < 8; il++) ak[il] = 0.f;
    #pragma unroll
    for (int dq = 0; dq < 16; dq++){
      float4 h4 = *(const float4*)&s_x[nl*68 + 4*dq];
      #pragma unroll
      for (int il = 0; il < 8; il++){
        int a = grp*8 + il;
        ak[il] += h4.x*wk[(4*dq+0)*64+a] + h4.y*wk[(4*dq+1)*64+a]
                + h4.z*wk[(4*dq+2)*64+a] + h4.w*wk[(4*dq+3)*64+a];
      }
    }
    #pragma unroll
    for (int il = 0; il < 8; il++) s_k[(grp*8+il)*32 + nl] = ak[il];
  }
  {
    float av[8];
    #pragma unroll
    for (int il = 0; il < 8; il++) av[il] = bv[grp*8+il];
    #pragma unroll
    for (int dq = 0; dq < 16; dq++){
      float4 h4 = *(const float4*)&s_x[nl*68 + 4*dq];
      #pragma unroll
      for (int il = 0; il < 8; il++){
        int a = grp*8 + il;
        av[il] += h4.x*wv[(4*dq+0)*64+a] + h4.y*wv[(4*dq+1)*64+a]
                + h4.z*wv[(4*dq+2)*64+a] + h4.w*wv[(4*dq+3)*64+a];
      }
    }
    #pragma unroll
    for (int il = 0; il < 8; il++) s_v[(grp*8+il)*32 + nl] = fmaxf(av[il], 0.f);
  }
  float aq[8];
  #pragma unroll
  for (int il = 0; il < 8; il++) aq[il] = 0.f;
  #pragma unroll
  for (int dq = 0; dq < 16; dq++){
    float4 h4 = *(const float4*)&s_x[nl*68 + 4*dq];
    #pragma unroll
    for (int il = 0; il < 8; il++){
      int a = grp*8 + il;
      aq[il] += h4.x*wq[(4*dq+0)*64+a] + h4.y*wq[(4*dq+1)*64+a]
              + h4.z*wq[(4*dq+2)*64+a] + h4.w*wq[(4*dq+3)*64+a];
    }
  }
  __syncthreads();

  const int i_b = nl & 15, jbase = nl & 16;
  #pragma unroll
  for (int t = 0; t < 15; t++){
    int jl = jbase | (t + (t >= i_b ? 1 : 0));
    float s = 0.f;
    #pragma unroll
    for (int il = 0; il < 8; il++) s += aq[il]*s_k[(grp*8+il)*32 + jl];
    s_sp[t*256 + grp*32 + nl] = s;
  }
  __syncthreads();

  float coeff[15];
  {
    float sc[15];
    float m = -1e30f;
    #pragma unroll
    for (int t = 0; t < 15; t++){
      float s = 0.f;
      #pragma unroll
      for (int g = 0; g < 8; g++) s += s_sp[t*256 + g*32 + nl];
      s *= 0.125f;
      sc[t] = s; m = fmaxf(m, s);
    }
    float den = 0.f;
    #pragma unroll
    for (int t = 0; t < 15; t++){ sc[t] = __expf(sc[t]-m); den += sc[t]; }
    float rden = 1.0f/den;
    const float bh0 = ws[OFF_BHARD], bh1 = ws[OFF_BHARD+1];
    const float* yF = ws + OFF_YF; const float* yB = ws + OFF_YB;
    #pragma unroll
    for (int t = 0; t < 15; t++){
      int rowb = (node*15 + t)*2;
      float y0 = yF[rowb]   + yB[rowb]   + bh0;
      float y1 = yF[rowb+1] + yB[rowb+1] + bh1;
      float2 u2 = *(const float2*)&gum[rowb];
      float g0 = -__logf(-__logf(u2.x + EPSG) + EPSG);
      float g1 = -__logf(-__logf(u2.y + EPSG) + EPSG);
      float w  = sigf(((y1+g1) - (y0+g0)) * (1.0f/TAU_));
      coeff[t] = sc[t]*rden*w;
    }
  }

  {
    float xa[8];
    #pragma unroll
    for (int il = 0; il < 8; il++) xa[il] = 0.f;
    #pragma unroll
    for (int t = 0; t < 15; t++){
      int jl = jbase | (t + (t >= i_b ? 1 : 0));
      float c = coeff[t];
      #pragma unroll
      for (int il = 0; il < 8; il++) xa[il] += c*s_v[(grp*8+il)*32 + jl];
    }
    __syncthreads();
    #pragma unroll
    for (int il = 0; il < 8; il++) s_x[nl*68 + grp*8 + il] = xa[il];
  }

  for (int k = tid; k < 2048; k += 256)
    s_h0[(k>>6)*68 + (k&63)] = hid[base*64 + k];
  __syncthreads();

  const float* wih = ws+OFF_WIHC; const float* whc = ws+OFF_WHHC;
  const float* bih = ws+OFF_BIHC; const float* bhc = ws+OFF_BHHC;
  for (int ilb = 0; ilb < 2; ilb++){
    float ac[24];
    #pragma unroll
    for (int p = 0; p < 4; p++){
      int l = grp*8 + ilb*4 + p;
      ac[p*6+0] = bih[l]; ac[p*6+1] = bih[64+l]; ac[p*6+2] = bih[128+l];
      ac[p*6+3] = bhc[l]; ac[p*6+4] = bhc[64+l]; ac[p*6+5] = bhc[128+l];
    }
    #pragma unroll
    for (int dq = 0; dq < 16; dq++){
      float4 x4 = *(const float4*)&s_x [nl*68 + 4*dq];
      float4 h4 = *(const float4*)&s_h0[nl*68 + 4*dq];
      #pragma unroll
      for (int p = 0; p < 4; p++){
        int l = grp*8 + ilb*4 + p;
        const float* w0 = wih + (l     )*64 + 4*dq;
        const float* w1 = wih + (64 + l)*64 + 4*dq;
        const float* w2 = wih + (128+ l)*64 + 4*dq;
        const float* m0 = whc + (l     )*64 + 4*dq;
        const float* m1 = whc + (64 + l)*64 + 4*dq;
        const float* m2 = whc + (128+ l)*64 + 4*dq;
        ac[p*6+0] += x4.x*w0[0]+x4.y*w0[1]+x4.z*w0[2]+x4.w*w0[3];
        ac[p*6+1] += x4.x*w1[0]+x4.y*w1[1]+x4.z*w1[2]+x4.w*w1[3];
        ac[p*6+2] += x4.x*w2[0]+x4.y*w2[1]+x4.z*w2[2]+x4.w*w2[3];
        ac[p*6+3] += h4.x*m0[0]+h4.y*m0[1]+h4.z*m0[2]+h4.w*m0[3];
        ac[p*6+4] += h4.x*m1[0]+h4.y*m1[1]+h4.z*m1[2]+h4.w*m1[3];
        ac[p*6+5] += h4.x*m2[0]+h4.y*m2[1]+h4.z*m2[2]+h4.w*m2[3];
      }
    }
    #pragma unroll
    for (int p = 0; p < 4; p++){
      int l = grp*8 + ilb*4 + p;
      float r = sigf(ac[p*6+0] + ac[p*6+3]);
      float z = sigf(ac[p*6+1] + ac[p*6+4]);
      float n = tanhfast(ac[p*6+2] + r*ac[p*6+5]);
      out[node*64 + l] = (1.0f - z)*n + z*s_h0[nl*68 + l];
    }
  }
}

extern "C" void kernel_launch(void* const* d_in, const int* in_sizes, int n_in,
                              void* d_out, int out_size, void* d_ws, size_t ws_size,
                              hipStream_t stream){
  if (ws_size < (size_t)WS_FLOATS * sizeof(float)) return;
  float* ws = (float*)d_ws;
  // f32 copies still needed (Wih/Whh slots now hold bf16 splits from k_prep2)
  static const int offs[20] = {OFF_WENC, OFF_BENC, 0, 0, OFF_BIHF, OFF_BHHF,
      0, 0, OFF_BIHB, OFF_BHHB, OFF_WHARD, OFF_BHARD, OFF_WQ, OFF_WK, OFF_WV,
      OFF_BV, OFF_WIHC, OFF_WHHC, OFF_BIHC, OFF_BHHC};
  Prep p;
  for (int i = 0; i < 20; i++){
    p.s[i] = (const float*)d_in[3 + i];
    p.n[i] = in_sizes[3 + i];
    p.o[i] = offs[i];
  }
  p.n[2] = 0; p.n[3] = 0; p.n[6] = 0; p.n[7] = 0;   // Wih_f/Whh_f/Wih_b/Whh_b: bf16 path
  hipLaunchKernelGGL(k_prep, dim3(96, 20), dim3(256), 0, stream, p, ws);
  hipLaunchKernelGGL(k_prep2, dim3(96, 5), dim3(256), 0, stream,
                     (const float*)d_in[3], (const float*)d_in[5], (const float*)d_in[9],
                     (const float*)d_in[6], (const float*)d_in[10], ws);
  hipLaunchKernelGGL(k_gru,  dim3(512),    dim3(512), 0, stream,
                     (const float*)d_in[0], ws);
  hipLaunchKernelGGL(k_attn, dim3(512),    dim3(256), 0, stream,
                     (const float*)d_in[0], (const float*)d_in[1],
                     (const float*)d_in[2], ws, (float*)d_out);
}

// Round 5
// 230.107 us; speedup vs baseline: 2.3116x; 2.3116x over previous
//
#include <hip/hip_runtime.h>
#include <hip/hip_bf16.h>
#include <stdint.h>

// B=1024, N=16, D=64, H=64, A=64 -> 16384 nodes. All tensors fp32.
#define NNODE 16384
#define TAU_ 0.01f
#define EPSG 1e-10f

// ---- workspace layout (float offsets); total 1,114,112 floats = 4.25 MB ----
#define OFF_WENC 0
#define OFF_BENC 4096
#define OFF_WIHF_H 4160      // 192x128 bf16 = 24576 ushort = 12288 fl
#define OFF_WIHF_L 16448
#define OFF_WHHF_H 28736     // 192x64 bf16 hi
#define OFF_BIHF 41024
#define OFF_BHHF 41216
#define OFF_WIHB_H 41408
#define OFF_WIHB_L 53696
#define OFF_WHHB_H 65984
#define OFF_BIHB 78272
#define OFF_BHHB 78464
#define OFF_WHARD 78656
#define OFF_BHARD 78912
// bf16 hi/lo splits for k_attn MFMA (reuse old f32 Wq/Wk/Wv/Wihc/Whhc slots)
#define OFF_WQT_H 78914      // Wq^T 64x64: 4096 ushort = 2048 fl
#define OFF_WQT_L 80962
#define OFF_WKT_H 83010
#define OFF_WKT_L 85058
#define OFF_WVT_H 87106
#define OFF_WVT_L 89154
#define OFF_BV 91202
#define OFF_WIHC_H 91266     // 192x64: 12288 ushort = 6144 fl
#define OFF_WIHC_L 97410
#define OFF_WHHC_H 103554
#define OFF_WHHC_L 109698
#define OFF_BIHC 115842
#define OFF_BHHC 116034
#define OFF_WENCT_H 118784   // Wenc^T bf16 hi: 64x64
#define OFF_WENCT_L 120832
#define OFF_YF 131072
#define OFF_YB (OFF_YF + 491520)
#define WS_FLOATS (OFF_YB + 491520)

typedef float  v4f __attribute__((ext_vector_type(4)));
typedef short  v8s __attribute__((ext_vector_type(8)));

__device__ __forceinline__ float sigf(float x){ return 1.0f/(1.0f + __expf(-x)); }
__device__ __forceinline__ float tanhfast(float x){ return 1.0f - 2.0f/(__expf(2.0f*x)+1.0f); }
__device__ __forceinline__ unsigned short f2bf(float f){
  __hip_bfloat16 h = __float2bfloat16(f);
  return *reinterpret_cast<unsigned short*>(&h);
}
__device__ __forceinline__ float bf2f(unsigned short u){
  union { unsigned int i; float f; } v; v.i = ((unsigned int)u) << 16; return v.f;
}

// ---------------- K0: copy f32 weights still needed as f32 ----------------
struct Prep {
  const float* s[20];
  int n[20];
  int o[20];
};
__global__ void k_prep(Prep p, float* __restrict__ ws){
  int a = blockIdx.y;
  int i = blockIdx.x * blockDim.x + threadIdx.x;
  if (i < p.n[a]) ws[p.o[a] + i] = p.s[a][i];
}

// ---------------- K0b: bf16 hi/lo splits of the MFMA weights ----------------
// a=0 WencT (transpose+split), a=1/2 Wih_f/b (flat), a=3/4 Whh_f/b (hi only),
// a=5/6/7 WqT/WkT/WvT (transpose+split), a=8/9 Wihc/Whhc (flat split).
__global__ void k_prep2(const float* __restrict__ wenc,
                        const float* __restrict__ wihf, const float* __restrict__ wihb,
                        const float* __restrict__ whhf, const float* __restrict__ whhb,
                        const float* __restrict__ wq,   const float* __restrict__ wk,
                        const float* __restrict__ wv,   const float* __restrict__ wihc,
                        const float* __restrict__ whhc,
                        float* __restrict__ ws){
  int a = blockIdx.y;
  int i = blockIdx.x * blockDim.x + threadIdx.x;
  if (a == 0 || (a >= 5 && a <= 7)){
    if (i < 4096){
      const float* src = (a==0) ? wenc : (a==5) ? wq : (a==6) ? wk : wv;
      int oh = (a==0) ? OFF_WENCT_H : (a==5) ? OFF_WQT_H : (a==6) ? OFF_WKT_H : OFF_WVT_H;
      int ol = (a==0) ? OFF_WENCT_L : oh + 2048;
      float x = src[((i & 63) << 6) | (i >> 6)];   // T[r][c] = src[c][r]
      unsigned short h = f2bf(x);
      unsigned short l = f2bf(x - bf2f(h));
      ((unsigned short*)(ws + oh))[i] = h;
      ((unsigned short*)(ws + ol))[i] = l;
    }
  } else if (a == 1 || a == 2){
    if (i < 24576){
      float x = (a == 1 ? wihf : wihb)[i];
      unsigned short h = f2bf(x);
      unsigned short l = f2bf(x - bf2f(h));
      ((unsigned short*)(ws + (a == 1 ? OFF_WIHF_H : OFF_WIHB_H)))[i] = h;
      ((unsigned short*)(ws + (a == 1 ? OFF_WIHF_L : OFF_WIHB_L)))[i] = l;
    }
  } else if (a == 3 || a == 4){
    if (i < 12288){
      float x = (a == 3 ? whhf : whhb)[i];
      ((unsigned short*)(ws + (a == 3 ? OFF_WHHF_H : OFF_WHHB_H)))[i] = f2bf(x);
    }
  } else {
    if (i < 12288){
      float x = (a == 8 ? wihc : whhc)[i];
      unsigned short h = f2bf(x);
      unsigned short l = f2bf(x - bf2f(h));
      int oh = (a == 8 ? OFF_WIHC_H : OFF_WHHC_H);
      ((unsigned short*)(ws + oh))[i] = h;
      ((unsigned short*)(ws + oh + 6144))[i] = l;
    }
  }
}

// ---------------- K1: bidirectional 15-step GRU via bf16 MFMA ---------------
// (unchanged from R3: MFMA setup + distributed y-reducer)
__global__ __launch_bounds__(512, 2) void k_gru(const float* __restrict__ obs,
                                                float* __restrict__ ws){
  __shared__ float smem[18432];               // 72 KB -> 2 blocks/CU
  float* s_u2 = smem;                         // [j-node][196] rows g*64+l : 12544
  unsigned short* s_obs_h = (unsigned short*)(smem + 12544); // obs/h_enc hi [64][72]
  unsigned short* s_obs_l = s_obs_h + 4608;                  // lo [64][72]
  unsigned short* s_hbu   = (unsigned short*)(smem + 12544); // loop h: 2 x [64][88] (aliases)
  float* s_red = smem + 18176;                // 2 x [64][2] y-partials (parity)

  const int tid = threadIdx.x;
  const int nl  = tid & 63;
  const int grp = __builtin_amdgcn_readfirstlane(tid >> 6);
  const int dir = blockIdx.x >> 8;
  const int base = (blockIdx.x & 255) * 64;
  const int lw = grp >> 2;
  const int nw = grp & 3;
  const int q  = nl >> 4;
  const int i_c = nl & 15;
  const int node = 16*nw + i_c;

  // P0: stage obs as bf16 hi/lo [node][72]
  {
    float4 a = *(const float4*)&obs[base*64 + tid*8];
    float4 b = *(const float4*)&obs[base*64 + tid*8 + 4];
    int nn = tid >> 3, d0 = (tid & 7)*8;
    union { v8s v; unsigned short u[8]; } H, L;
    float xs[8] = {a.x,a.y,a.z,a.w,b.x,b.y,b.z,b.w};
    #pragma unroll
    for (int e = 0; e < 8; e++){
      H.u[e] = f2bf(xs[e]);
      L.u[e] = f2bf(xs[e] - bf2f(H.u[e]));
    }
    *(v8s*)&s_obs_h[nn*72 + d0] = H.v;
    *(v8s*)&s_obs_l[nn*72 + d0] = L.v;
  }
  __syncthreads();

  // P1: h_enc = relu(obs @ Wenc + b_enc) via MFMA
  const float* benc = ws + OFF_BENC;
  const unsigned short* wtH = (const unsigned short*)(ws + OFF_WENCT_H);
  const unsigned short* wtL = (const unsigned short*)(ws + OFF_WENCT_L);
  v4f dEnc[2];
  {
    v8s obH[2], obL[2];
    #pragma unroll
    for (int kc = 0; kc < 2; kc++){
      int ba = node*72 + kc*32 + q*8;
      obH[kc] = *(const v8s*)&s_obs_h[ba];
      obL[kc] = *(const v8s*)&s_obs_l[ba];
    }
    #pragma unroll
    for (int tt = 0; tt < 2; tt++){
      int lT = 2*lw + tt;
      float4 bi = *(const float4*)&benc[16*lT + 4*q];
      v4f d = (v4f){bi.x, bi.y, bi.z, bi.w};
      #pragma unroll
      for (int kc = 0; kc < 2; kc++){
        int aa = (16*lT + i_c)*64 + kc*32 + q*8;
        v8s aH = *(const v8s*)&wtH[aa];
        v8s aL = *(const v8s*)&wtL[aa];
        d = __builtin_amdgcn_mfma_f32_16x16x32_bf16(aH, obH[kc], d, 0,0,0);
        d = __builtin_amdgcn_mfma_f32_16x16x32_bf16(aH, obL[kc], d, 0,0,0);
        d = __builtin_amdgcn_mfma_f32_16x16x32_bf16(aL, obH[kc], d, 0,0,0);
      }
      dEnc[tt] = d;
    }
  }
  __syncthreads();
  #pragma unroll
  for (int tt = 0; tt < 2; tt++){
    int lT = 2*lw + tt;
    unsigned short hh[4], ll[4];
    #pragma unroll
    for (int r = 0; r < 4; r++){
      float v = fmaxf(dEnc[tt][r], 0.0f);
      hh[r] = f2bf(v);
      ll[r] = f2bf(v - bf2f(hh[r]));
    }
    int wa = node*72 + 16*lT + 4*q;
    *(uint2*)&s_obs_h[wa] = make_uint2((unsigned)hh[0] | ((unsigned)hh[1]<<16),
                                       (unsigned)hh[2] | ((unsigned)hh[3]<<16));
    *(uint2*)&s_obs_l[wa] = make_uint2((unsigned)ll[0] | ((unsigned)ll[1]<<16),
                                       (unsigned)ll[2] | ((unsigned)ll[3]<<16));
  }
  __syncthreads();

  const float* bih = ws + (dir ? OFF_BIHB : OFF_BIHF);
  const float* bhh = ws + (dir ? OFF_BHHB : OFF_BHHF);
  const unsigned short* wiH = (const unsigned short*)(ws + (dir ? OFF_WIHB_H : OFF_WIHF_H));
  const unsigned short* wiL = (const unsigned short*)(ws + (dir ? OFF_WIHB_L : OFF_WIHF_L));
  const unsigned short* whH = (const unsigned short*)(ws + (dir ? OFF_WHHB_H : OFF_WHHF_H));

  v8s hbH[2], hbL[2];
  #pragma unroll
  for (int kc = 0; kc < 2; kc++){
    int ba = node*72 + kc*32 + q*8;
    hbH[kc] = *(const v8s*)&s_obs_h[ba];
    hbL[kc] = *(const v8s*)&s_obs_l[ba];
  }

  // P2a: u2
  #pragma unroll
  for (int m = 0; m < 6; m++){
    int T = 6*lw + m;
    v4f d = (v4f){0.f,0.f,0.f,0.f};
    #pragma unroll
    for (int kc = 0; kc < 2; kc++){
      int aa = (16*T + i_c)*128 + 64 + kc*32 + q*8;
      v8s aH = *(const v8s*)&wiH[aa];
      v8s aL = *(const v8s*)&wiL[aa];
      d = __builtin_amdgcn_mfma_f32_16x16x32_bf16(aH, hbH[kc], d, 0,0,0);
      d = __builtin_amdgcn_mfma_f32_16x16x32_bf16(aH, hbL[kc], d, 0,0,0);
      d = __builtin_amdgcn_mfma_f32_16x16x32_bf16(aL, hbH[kc], d, 0,0,0);
    }
    *(v4f*)&s_u2[node*196 + 16*T + 4*q] = d;
  }

  // P2b: cb
  v4f cbr[2], cbz[2], cbn[2], bhn4[2];
  #pragma unroll
  for (int g = 0; g < 3; g++){
    #pragma unroll
    for (int t2 = 0; t2 < 2; t2++){
      int row0 = 64*g + 32*lw + 16*t2 + 4*q;
      float4 bi = *(const float4*)&bih[row0];
      v4f d;
      if (g < 2){
        float4 bh = *(const float4*)&bhh[row0];
        d = (v4f){bi.x+bh.x, bi.y+bh.y, bi.z+bh.z, bi.w+bh.w};
      } else {
        d = (v4f){bi.x, bi.y, bi.z, bi.w};
      }
      int T = (64*g + 32*lw + 16*t2) >> 4;
      #pragma unroll
      for (int kc = 0; kc < 2; kc++){
        int aa = (16*T + i_c)*128 + kc*32 + q*8;
        v8s aH = *(const v8s*)&wiH[aa];
        v8s aL = *(const v8s*)&wiL[aa];
        d = __builtin_amdgcn_mfma_f32_16x16x32_bf16(aH, hbH[kc], d, 0,0,0);
        d = __builtin_amdgcn_mfma_f32_16x16x32_bf16(aH, hbL[kc], d, 0,0,0);
        d = __builtin_amdgcn_mfma_f32_16x16x32_bf16(aL, hbH[kc], d, 0,0,0);
      }
      if (g == 0) cbr[t2] = d; else if (g == 1) cbz[t2] = d; else cbn[t2] = d;
    }
  }
  #pragma unroll
  for (int t2 = 0; t2 < 2; t2++){
    int row0 = 128 + 32*lw + 16*t2 + 4*q;
    float4 nh = *(const float4*)&bhh[row0];
    bhn4[t2] = (v4f){nh.x, nh.y, nh.z, nh.w};
  }

  // P2c: Whh A-frags
  v8s afr[2][2], afz[2][2], afn[2][2];
  #pragma unroll
  for (int t2 = 0; t2 < 2; t2++){
    #pragma unroll
    for (int kc = 0; kc < 2; kc++){
      #pragma unroll
      for (int g = 0; g < 3; g++){
        int row = g*64 + 32*lw + 16*t2 + i_c;
        v8s a = *(const v8s*)&whH[row*64 + kc*32 + q*8];
        if (g == 0) afr[t2][kc] = a; else if (g == 1) afz[t2][kc] = a; else afn[t2][kc] = a;
      }
    }
  }

  const float* whard = ws + OFF_WHARD + dir*128;
  float wh0[8], wh1[8];
  #pragma unroll
  for (int t2 = 0; t2 < 2; t2++){
    #pragma unroll
    for (int r = 0; r < 4; r++){
      int l = 32*lw + 16*t2 + 4*q + r;
      wh0[t2*4+r] = whard[l*2];
      wh1[t2*4+r] = whard[l*2+1];
    }
  }
  __syncthreads();

  // P3: 15-step recurrence
  float* yout = ws + (dir ? OFF_YB : OFF_YF);

  float hv[8];
  #pragma unroll
  for (int m = 0; m < 8; m++) hv[m] = 0.0f;

  for (int kk = 0; kk < 15; kk++){
    const int t  = dir ? (14 - kk) : kk;
    const int j  = t + (t >= i_c ? 1 : 0);
    const int jl = 16*nw + j;
    const int rb = kk & 1;
    const int wb = (kk + 1) & 1;

    v8s b0, b1;
    if (kk > 0){
      const unsigned short* rp = s_hbu + rb*5632 + node*88 + q*8;
      b0 = *(const v8s*)(rp);
      b1 = *(const v8s*)(rp + 32);
    }

    float a0p = 0.f, a1p = 0.f;
    #pragma unroll
    for (int t2 = 0; t2 < 2; t2++){
      int l0 = 32*lw + 16*t2 + 4*q;
      v4f dr = cbr[t2], dz = cbz[t2];
      v4f dn = (v4f){0.f,0.f,0.f,0.f};
      if (kk > 0){
        dr = __builtin_amdgcn_mfma_f32_16x16x32_bf16(afr[t2][0], b0, dr, 0,0,0);
        dr = __builtin_amdgcn_mfma_f32_16x16x32_bf16(afr[t2][1], b1, dr, 0,0,0);
        dz = __builtin_amdgcn_mfma_f32_16x16x32_bf16(afz[t2][0], b0, dz, 0,0,0);
        dz = __builtin_amdgcn_mfma_f32_16x16x32_bf16(afz[t2][1], b1, dz, 0,0,0);
        dn = __builtin_amdgcn_mfma_f32_16x16x32_bf16(afn[t2][0], b0, dn, 0,0,0);
        dn = __builtin_amdgcn_mfma_f32_16x16x32_bf16(afn[t2][1], b1, dn, 0,0,0);
      }
      v4f ur = *(const v4f*)&s_u2[jl*196 +       l0];
      v4f uz = *(const v4f*)&s_u2[jl*196 +  64 + l0];
      v4f un = *(const v4f*)&s_u2[jl*196 + 128 + l0];
      float hn[4];
      #pragma unroll
      for (int r = 0; r < 4; r++){
        float rg = sigf(dr[r] + ur[r]);
        float zg = sigf(dz[r] + uz[r]);
        float ng = tanhfast(cbn[t2][r] + un[r] + rg*(bhn4[t2][r] + dn[r]));
        float hnew = (1.0f - zg)*ng + zg*hv[t2*4+r];
        hv[t2*4+r] = hnew;
        hn[r] = hnew;
        a0p += hnew*wh0[t2*4+r];
        a1p += hnew*wh1[t2*4+r];
      }
      unsigned int p0 = (unsigned int)f2bf(hn[0]) | ((unsigned int)f2bf(hn[1]) << 16);
      unsigned int p1 = (unsigned int)f2bf(hn[2]) | ((unsigned int)f2bf(hn[3]) << 16);
      *(uint2*)(s_hbu + wb*5632 + node*88 + l0) = make_uint2(p0, p1);
    }

    a0p += __shfl_xor(a0p, 16); a0p += __shfl_xor(a0p, 32);
    a1p += __shfl_xor(a1p, 16); a1p += __shfl_xor(a1p, 32);
    float* sr = s_red + rb*128;
    if (lw == 0 && q == 0)
      *(float2*)&sr[node*2] = make_float2(a0p, a1p);
    __syncthreads();
    if (lw == 1 && q == 0){
      float2 pp = *(const float2*)&sr[node*2];
      *(float2*)&yout[((base + node)*15 + t)*2] = make_float2(a0p + pp.x, a1p + pp.y);
    }
  }
}

// ---------------- K2: qkv + gumbel + attention + final GRU cell -------------
// REBUILT on the k_gru skeleton (measured spill-free): 256 blocks x 64 nodes,
// 512 thr / 8 waves.  h_enc, q/k/v, and the final GRU GEMMs are split-bf16
// MFMA; scores/softmax/gumbel/PV are VALU with 8-lane shfl reduce.
// launch_bounds(512,1): grid 256 = 1 block/CU anyway; 256-VGPR cap = no spill.
__global__ __launch_bounds__(512, 1) void k_attn(const float* __restrict__ obs,
                                                 const float* __restrict__ hid,
                                                 const float* __restrict__ gum,
                                                 float* __restrict__ ws,
                                                 float* __restrict__ out){
  __shared__ float smem[14336];                        // 56 KB
  unsigned short* s_obs_h = (unsigned short*)smem;     // [64][72] obs/h_enc hi
  unsigned short* s_obs_l = s_obs_h + 4608;            // lo
  float* s_q  = smem;                                  // [64][68] fp32 (aliases, after frags)
  unsigned short* s_h0h = (unsigned short*)smem;       // h0 hi (aliases, late)
  unsigned short* s_h0l = s_h0h + 4608;
  float* s_k  = smem + 4608;                           // [64][65]
  unsigned short* s_xh = (unsigned short*)(smem + 4608); // x frags (alias s_k, late)
  unsigned short* s_xl = s_xh + 4608;
  float* s_v  = smem + 9216;                           // [64][65]
  float* s_co = smem + 13376;                          // [15][64]

  const int tid = threadIdx.x;
  const int nl  = tid & 63;
  const int grp = __builtin_amdgcn_readfirstlane(tid >> 6);
  const int base = blockIdx.x * 64;
  const int lw = grp >> 2;
  const int nw = grp & 3;
  const int q4 = nl >> 4;
  const int i_c = nl & 15;
  const int node = 16*nw + i_c;

  // P0: stage obs bf16 hi/lo [node][72]
  {
    float4 a = *(const float4*)&obs[base*64 + tid*8];
    float4 b = *(const float4*)&obs[base*64 + tid*8 + 4];
    int nn = tid >> 3, d0 = (tid & 7)*8;
    union { v8s v; unsigned short u[8]; } H, L;
    float xs[8] = {a.x,a.y,a.z,a.w,b.x,b.y,b.z,b.w};
    #pragma unroll
    for (int e = 0; e < 8; e++){
      H.u[e] = f2bf(xs[e]);
      L.u[e] = f2bf(xs[e] - bf2f(H.u[e]));
    }
    *(v8s*)&s_obs_h[nn*72 + d0] = H.v;
    *(v8s*)&s_obs_l[nn*72 + d0] = L.v;
  }
  __syncthreads();

  // P1: h_enc via MFMA (same as k_gru)
  const float* benc = ws + OFF_BENC;
  const unsigned short* wtH = (const unsigned short*)(ws + OFF_WENCT_H);
  const unsigned short* wtL = (const unsigned short*)(ws + OFF_WENCT_L);
  v4f dEnc[2];
  {
    v8s obH[2], obL[2];
    #pragma unroll
    for (int kc = 0; kc < 2; kc++){
      int ba = node*72 + kc*32 + q4*8;
      obH[kc] = *(const v8s*)&s_obs_h[ba];
      obL[kc] = *(const v8s*)&s_obs_l[ba];
    }
    #pragma unroll
    for (int tt = 0; tt < 2; tt++){
      int lT = 2*lw + tt;
      float4 bi = *(const float4*)&benc[16*lT + 4*q4];
      v4f d = (v4f){bi.x, bi.y, bi.z, bi.w};
      #pragma unroll
      for (int kc = 0; kc < 2; kc++){
        int aa = (16*lT + i_c)*64 + kc*32 + q4*8;
        v8s aH = *(const v8s*)&wtH[aa];
        v8s aL = *(const v8s*)&wtL[aa];
        d = __builtin_amdgcn_mfma_f32_16x16x32_bf16(aH, obH[kc], d, 0,0,0);
        d = __builtin_amdgcn_mfma_f32_16x16x32_bf16(aH, obL[kc], d, 0,0,0);
        d = __builtin_amdgcn_mfma_f32_16x16x32_bf16(aL, obH[kc], d, 0,0,0);
      }
      dEnc[tt] = d;
    }
  }
  __syncthreads();
  #pragma unroll
  for (int tt = 0; tt < 2; tt++){
    int lT = 2*lw + tt;
    unsigned short hh[4], ll[4];
    #pragma unroll
    for (int r = 0; r < 4; r++){
      float v = fmaxf(dEnc[tt][r], 0.0f);
      hh[r] = f2bf(v);
      ll[r] = f2bf(v - bf2f(hh[r]));
    }
    int wa = node*72 + 16*lT + 4*q4;
    *(uint2*)&s_obs_h[wa] = make_uint2((unsigned)hh[0] | ((unsigned)hh[1]<<16),
                                       (unsigned)hh[2] | ((unsigned)hh[3]<<16));
    *(uint2*)&s_obs_l[wa] = make_uint2((unsigned)ll[0] | ((unsigned)ll[1]<<16),
                                       (unsigned)ll[2] | ((unsigned)ll[3]<<16));
  }
  __syncthreads();

  // C: h_enc B-frags; q/k/v MFMA (registers only)
  v8s hbH[2], hbL[2];
  #pragma unroll
  for (int kc = 0; kc < 2; kc++){
    int ba = node*72 + kc*32 + q4*8;
    hbH[kc] = *(const v8s*)&s_obs_h[ba];
    hbL[kc] = *(const v8s*)&s_obs_l[ba];
  }
  const unsigned short* wqH = (const unsigned short*)(ws + OFF_WQT_H);
  const unsigned short* wqL = (const unsigned short*)(ws + OFF_WQT_L);
  const unsigned short* wkH = (const unsigned short*)(ws + OFF_WKT_H);
  const unsigned short* wkL = (const unsigned short*)(ws + OFF_WKT_L);
  const unsigned short* wvH = (const unsigned short*)(ws + OFF_WVT_H);
  const unsigned short* wvL = (const unsigned short*)(ws + OFF_WVT_L);
  const float* bv = ws + OFF_BV;
  v4f dq[2], dk[2], dv[2];
  #pragma unroll
  for (int a2 = 0; a2 < 2; a2++){
    int aT = 2*lw + a2;
    v4f q_ = (v4f){0.f,0.f,0.f,0.f};
    v4f k_ = (v4f){0.f,0.f,0.f,0.f};
    float4 b4 = *(const float4*)&bv[16*aT + 4*q4];
    v4f v_ = (v4f){b4.x, b4.y, b4.z, b4.w};
    #pragma unroll
    for (int kc = 0; kc < 2; kc++){
      int ai = (16*aT + i_c)*64 + kc*32 + q4*8;
      v8s aH = *(const v8s*)&wqH[ai]; v8s aL = *(const v8s*)&wqL[ai];
      q_ = __builtin_amdgcn_mfma_f32_16x16x32_bf16(aH, hbH[kc], q_, 0,0,0);
      q_ = __builtin_amdgcn_mfma_f32_16x16x32_bf16(aH, hbL[kc], q_, 0,0,0);
      q_ = __builtin_amdgcn_mfma_f32_16x16x32_bf16(aL, hbH[kc], q_, 0,0,0);
      aH = *(const v8s*)&wkH[ai]; aL = *(const v8s*)&wkL[ai];
      k_ = __builtin_amdgcn_mfma_f32_16x16x32_bf16(aH, hbH[kc], k_, 0,0,0);
      k_ = __builtin_amdgcn_mfma_f32_16x16x32_bf16(aH, hbL[kc], k_, 0,0,0);
      k_ = __builtin_amdgcn_mfma_f32_16x16x32_bf16(aL, hbH[kc], k_, 0,0,0);
      aH = *(const v8s*)&wvH[ai]; aL = *(const v8s*)&wvL[ai];
      v_ = __builtin_amdgcn_mfma_f32_16x16x32_bf16(aH, hbH[kc], v_, 0,0,0);
      v_ = __builtin_amdgcn_mfma_f32_16x16x32_bf16(aH, hbL[kc], v_, 0,0,0);
      v_ = __builtin_amdgcn_mfma_f32_16x16x32_bf16(aL, hbH[kc], v_, 0,0,0);
    }
    dq[a2] = q_; dk[a2] = k_; dv[a2] = v_;
  }
  __syncthreads();   // all s_obs frag reads done -> s_q (alias) writable

  // D: store q [node][68], k/v [a][65]
  #pragma unroll
  for (int a2 = 0; a2 < 2; a2++){
    int aT = 2*lw + a2;
    *(v4f*)&s_q[node*68 + 16*aT + 4*q4] = dq[a2];
    #pragma unroll
    for (int r = 0; r < 4; r++){
      s_k[(16*aT + 4*q4 + r)*65 + node] = dk[a2][r];
      s_v[(16*aT + 4*q4 + r)*65 + node] = fmaxf(dv[a2][r], 0.f);
    }
  }
  __syncthreads();

  // E: scores + softmax + gumbel coeffs.  Remap: n2 = node, asl = a-slice.
  const int n2  = tid >> 3;
  const int asl = tid & 7;
  const int ib2 = n2 & 15, jb2 = n2 & 48;
  float4 aq0 = *(const float4*)&s_q[n2*68 + asl*8];
  float4 aq1 = *(const float4*)&s_q[n2*68 + asl*8 + 4];
  float sc[15];
  #pragma unroll
  for (int t = 0; t < 15; t++){
    int jl = jb2 | (t + (t >= ib2 ? 1 : 0));
    const float* kp = s_k + (asl*8)*65 + jl;
    float s = aq0.x*kp[0]   + aq0.y*kp[65]  + aq0.z*kp[130] + aq0.w*kp[195]
            + aq1.x*kp[260] + aq1.y*kp[325] + aq1.z*kp[390] + aq1.w*kp[455];
    s += __shfl_xor(s, 1); s += __shfl_xor(s, 2); s += __shfl_xor(s, 4);
    sc[t] = s * 0.125f;
  }
  {
    float m = sc[0];
    #pragma unroll
    for (int t = 1; t < 15; t++) m = fmaxf(m, sc[t]);
    float den = 0.f;
    #pragma unroll
    for (int t = 0; t < 15; t++) den += __expf(sc[t]-m);
    float rden = 1.0f/den;
    const float bh0 = ws[OFF_BHARD], bh1 = ws[OFF_BHARD+1];
    const float* yF = ws + OFF_YF; const float* yB = ws + OFF_YB;
    #pragma unroll
    for (int t = 0; t < 15; t++){
      if ((t & 7) == asl){
        int rowb = ((base + n2)*15 + t)*2;
        float y0 = yF[rowb]   + yB[rowb]   + bh0;
        float y1 = yF[rowb+1] + yB[rowb+1] + bh1;
        float2 u2 = *(const float2*)&gum[rowb];
        float g0 = -__logf(-__logf(u2.x + EPSG) + EPSG);
        float g1 = -__logf(-__logf(u2.y + EPSG) + EPSG);
        float w  = sigf(((y1+g1) - (y0+g0)) * (1.0f/TAU_));
        s_co[t*64 + n2] = __expf(sc[t]-m)*rden*w;
      }
    }
  }
  __syncthreads();

  // F: x = sum_t coeff * v  (8 a's per thread), write x bf16 frags; stage h0
  {
    float xa[8];
    #pragma unroll
    for (int il = 0; il < 8; il++) xa[il] = 0.f;
    #pragma unroll
    for (int t = 0; t < 15; t++){
      float c = s_co[t*64 + n2];
      int jl = jb2 | (t + (t >= ib2 ? 1 : 0));
      const float* vp = s_v + (asl*8)*65 + jl;
      xa[0] += c*vp[0];   xa[1] += c*vp[65];  xa[2] += c*vp[130]; xa[3] += c*vp[195];
      xa[4] += c*vp[260]; xa[5] += c*vp[325]; xa[6] += c*vp[390]; xa[7] += c*vp[455];
    }
    union { v8s v; unsigned short u[8]; } XH, XL;
    #pragma unroll
    for (int e = 0; e < 8; e++){
      XH.u[e] = f2bf(xa[e]);
      XL.u[e] = f2bf(xa[e] - bf2f(XH.u[e]));
    }
    *(v8s*)&s_xh[n2*72 + asl*8] = XH.v;
    *(v8s*)&s_xl[n2*72 + asl*8] = XL.v;
  }
  {
    float4 a = *(const float4*)&hid[base*64 + tid*8];
    float4 b = *(const float4*)&hid[base*64 + tid*8 + 4];
    int nn = tid >> 3, d0 = (tid & 7)*8;
    union { v8s v; unsigned short u[8]; } H, L;
    float xs[8] = {a.x,a.y,a.z,a.w,b.x,b.y,b.z,b.w};
    #pragma unroll
    for (int e = 0; e < 8; e++){
      H.u[e] = f2bf(xs[e]);
      L.u[e] = f2bf(xs[e] - bf2f(H.u[e]));
    }
    *(v8s*)&s_h0h[nn*72 + d0] = H.v;
    *(v8s*)&s_h0l[nn*72 + d0] = L.v;
  }
  __syncthreads();

  // G: final GRU cell via MFMA: gi = Wihc.x, gh = Whhc.h0
  v8s xbH[2], xbL[2], h0H[2], h0L[2];
  #pragma unroll
  for (int kc = 0; kc < 2; kc++){
    int ba = node*72 + kc*32 + q4*8;
    xbH[kc] = *(const v8s*)&s_xh[ba];  xbL[kc] = *(const v8s*)&s_xl[ba];
    h0H[kc] = *(const v8s*)&s_h0h[ba]; h0L[kc] = *(const v8s*)&s_h0l[ba];
  }
  const unsigned short* wiH = (const unsigned short*)(ws + OFF_WIHC_H);
  const unsigned short* wiL = (const unsigned short*)(ws + OFF_WIHC_L);
  const unsigned short* whH = (const unsigned short*)(ws + OFF_WHHC_H);
  const unsigned short* whL = (const unsigned short*)(ws + OFF_WHHC_L);
  const float* bihc = ws + OFF_BIHC; const float* bhhc = ws + OFF_BHHC;
  v4f gi[3][2], gh[3][2];
  #pragma unroll
  for (int g = 0; g < 3; g++){
    #pragma unroll
    for (int u2 = 0; u2 < 2; u2++){
      int u = 2*lw + u2;
      int row0 = g*64 + 16*u + 4*q4;
      float4 bi = *(const float4*)&bihc[row0];
      float4 bh = *(const float4*)&bhhc[row0];
      v4f di, dh;
      if (g < 2){
        di = (v4f){bi.x+bh.x, bi.y+bh.y, bi.z+bh.z, bi.w+bh.w};
        dh = (v4f){0.f,0.f,0.f,0.f};
      } else {
        di = (v4f){bi.x, bi.y, bi.z, bi.w};
        dh = (v4f){bh.x, bh.y, bh.z, bh.w};
      }
      #pragma unroll
      for (int kc = 0; kc < 2; kc++){
        int ai = (g*64 + 16*u + i_c)*64 + kc*32 + q4*8;
        v8s aH = *(const v8s*)&wiH[ai]; v8s aL = *(const v8s*)&wiL[ai];
        di = __builtin_amdgcn_mfma_f32_16x16x32_bf16(aH, xbH[kc], di, 0,0,0);
        di = __builtin_amdgcn_mfma_f32_16x16x32_bf16(aH, xbL[kc], di, 0,0,0);
        di = __builtin_amdgcn_mfma_f32_16x16x32_bf16(aL, xbH[kc], di, 0,0,0);
        aH = *(const v8s*)&whH[ai]; aL = *(const v8s*)&whL[ai];
        dh = __builtin_amdgcn_mfma_f32_16x16x32_bf16(aH, h0H[kc], dh, 0,0,0);
        dh = __builtin_amdgcn_mfma_f32_16x16x32_bf16(aH, h0L[kc], dh, 0,0,0);
        dh = __builtin_amdgcn_mfma_f32_16x16x32_bf16(aL, h0H[kc], dh, 0,0,0);
      }
      gi[g][u2] = di; gh[g][u2] = dh;
    }
  }
  #pragma unroll
  for (int u2 = 0; u2 < 2; u2++){
    int l0 = 16*(2*lw + u2) + 4*q4;
    float4 h04 = *(const float4*)&hid[(base+node)*64 + l0];
    float hh[4] = {h04.x, h04.y, h04.z, h04.w};
    float ho[4];
    #pragma unroll
    for (int r = 0; r < 4; r++){
      float rg = sigf(gi[0][u2][r] + gh[0][u2][r]);
      float zg = sigf(gi[1][u2][r] + gh[1][u2][r]);
      float ng = tanhfast(gi[2][u2][r] + rg*gh[2][u2][r]);
      ho[r] = (1.0f - zg)*ng + zg*hh[r];
    }
    *(float4*)&out[(base+node)*64 + l0] = make_float4(ho[0], ho[1], ho[2], ho[3]);
  }
}

extern "C" void kernel_launch(void* const* d_in, const int* in_sizes, int n_in,
                              void* d_out, int out_size, void* d_ws, size_t ws_size,
                              hipStream_t stream){
  if (ws_size < (size_t)WS_FLOATS * sizeof(float)) return;
  float* ws = (float*)d_ws;
  // f32 copies still needed; MFMA weights go through k_prep2 bf16 splits
  static const int offs[20] = {OFF_WENC, OFF_BENC, 0, 0, OFF_BIHF, OFF_BHHF,
      0, 0, OFF_BIHB, OFF_BHHB, OFF_WHARD, OFF_BHARD, 0, 0, 0,
      OFF_BV, 0, 0, OFF_BIHC, OFF_BHHC};
  Prep p;
  for (int i = 0; i < 20; i++){
    p.s[i] = (const float*)d_in[3 + i];
    p.n[i] = in_sizes[3 + i];
    p.o[i] = offs[i];
  }
  // zero out f32 copies replaced by bf16 splits:
  p.n[2] = 0; p.n[3] = 0; p.n[6] = 0; p.n[7] = 0;      // Wih_f/Whh_f/Wih_b/Whh_b
  p.n[12] = 0; p.n[13] = 0; p.n[14] = 0;               // Wq/Wk/Wv
  p.n[16] = 0; p.n[17] = 0;                            // Wih_c/Whh_c
  hipLaunchKernelGGL(k_prep, dim3(96, 20), dim3(256), 0, stream, p, ws);
  hipLaunchKernelGGL(k_prep2, dim3(96, 10), dim3(256), 0, stream,
                     (const float*)d_in[3], (const float*)d_in[5], (const float*)d_in[9],
                     (const float*)d_in[6], (const float*)d_in[10],
                     (const float*)d_in[15], (const float*)d_in[16], (const float*)d_in[17],
                     (const float*)d_in[19], (const float*)d_in[20], ws);
  hipLaunchKernelGGL(k_gru,  dim3(512),    dim3(512), 0, stream,
                     (const float*)d_in[0], ws);
  hipLaunchKernelGGL(k_attn, dim3(256),    dim3(512), 0, stream,
                     (const float*)d_in[0], (const float*)d_in[1],
                     (const float*)d_in[2], ws, (float*)d_out);
}

// Round 6
// 206.816 us; speedup vs baseline: 2.5719x; 1.1126x over previous
//
#include <hip/hip_runtime.h>
#include <hip/hip_bf16.h>
#include <stdint.h>

// B=1024, N=16, D=64, H=64, A=64 -> 16384 nodes. All tensors fp32.
#define NNODE 16384
#define TAU_ 0.01f
#define EPSG 1e-10f

// ---- workspace layout (float offsets); total 1,114,112 floats = 4.25 MB ----
#define OFF_WENC 0
#define OFF_BENC 4096
#define OFF_WIHF_H 4160      // 192x128 bf16 = 24576 ushort = 12288 fl
#define OFF_WIHF_L 16448
#define OFF_WHHF_H 28736     // 192x64 bf16 hi
#define OFF_BIHF 41024
#define OFF_BHHF 41216
#define OFF_WIHB_H 41408
#define OFF_WIHB_L 53696
#define OFF_WHHB_H 65984
#define OFF_BIHB 78272
#define OFF_BHHB 78464
#define OFF_WHARD 78656
#define OFF_BHARD 78912
// bf16 hi/lo splits for k_attn MFMA (reuse old f32 Wq/Wk/Wv/Wihc/Whhc slots)
#define OFF_WQT_H 78914      // Wq^T 64x64: 4096 ushort = 2048 fl
#define OFF_WQT_L 80962
#define OFF_WKT_H 83010
#define OFF_WKT_L 85058
#define OFF_WVT_H 87106
#define OFF_WVT_L 89154
#define OFF_BV 91202
#define OFF_WIHC_H 91266     // 192x64: 12288 ushort = 6144 fl
#define OFF_WIHC_L 97410
#define OFF_WHHC_H 103554
#define OFF_WHHC_L 109698
#define OFF_BIHC 115842
#define OFF_BHHC 116034
#define OFF_WENCT_H 118784   // Wenc^T bf16 hi: 64x64
#define OFF_WENCT_L 120832
#define OFF_YF 131072
#define OFF_YB (OFF_YF + 491520)
#define WS_FLOATS (OFF_YB + 491520)

typedef float  v4f __attribute__((ext_vector_type(4)));
typedef short  v8s __attribute__((ext_vector_type(8)));

// v_rcp_f32 (1-ulp approx) instead of precise fp32 division: HIP's 1.0f/x
// emits div_scale+rcp+3xdiv_fmas+div_fixup (~9 ops, 2 quarter-rate).  The
// gate math runs 24 divisions/thread/step in k_gru -- this was ~1/3 of the
// VALU bill (R5 counters: 118k VALU-cycles/CU ~= gate-math estimate).
__device__ __forceinline__ float rcpf(float x){ return __builtin_amdgcn_rcpf(x); }
__device__ __forceinline__ float sigf(float x){ return rcpf(1.0f + __expf(-x)); }
__device__ __forceinline__ float tanhfast(float x){ return 1.0f - 2.0f*rcpf(__expf(2.0f*x)+1.0f); }
__device__ __forceinline__ unsigned short f2bf(float f){
  __hip_bfloat16 h = __float2bfloat16(f);
  return *reinterpret_cast<unsigned short*>(&h);
}
__device__ __forceinline__ float bf2f(unsigned short u){
  union { unsigned int i; float f; } v; v.i = ((unsigned int)u) << 16; return v.f;
}

// ---------------- K0: copy f32 weights still needed as f32 ----------------
struct Prep {
  const float* s[20];
  int n[20];
  int o[20];
};
__global__ void k_prep(Prep p, float* __restrict__ ws){
  int a = blockIdx.y;
  int i = blockIdx.x * blockDim.x + threadIdx.x;
  if (i < p.n[a]) ws[p.o[a] + i] = p.s[a][i];
}

// ---------------- K0b: bf16 hi/lo splits of the MFMA weights ----------------
// a=0 WencT (transpose+split), a=1/2 Wih_f/b (flat), a=3/4 Whh_f/b (hi only),
// a=5/6/7 WqT/WkT/WvT (transpose+split), a=8/9 Wihc/Whhc (flat split).
__global__ void k_prep2(const float* __restrict__ wenc,
                        const float* __restrict__ wihf, const float* __restrict__ wihb,
                        const float* __restrict__ whhf, const float* __restrict__ whhb,
                        const float* __restrict__ wq,   const float* __restrict__ wk,
                        const float* __restrict__ wv,   const float* __restrict__ wihc,
                        const float* __restrict__ whhc,
                        float* __restrict__ ws){
  int a = blockIdx.y;
  int i = blockIdx.x * blockDim.x + threadIdx.x;
  if (a == 0 || (a >= 5 && a <= 7)){
    if (i < 4096){
      const float* src = (a==0) ? wenc : (a==5) ? wq : (a==6) ? wk : wv;
      int oh = (a==0) ? OFF_WENCT_H : (a==5) ? OFF_WQT_H : (a==6) ? OFF_WKT_H : OFF_WVT_H;
      int ol = (a==0) ? OFF_WENCT_L : oh + 2048;
      float x = src[((i & 63) << 6) | (i >> 6)];   // T[r][c] = src[c][r]
      unsigned short h = f2bf(x);
      unsigned short l = f2bf(x - bf2f(h));
      ((unsigned short*)(ws + oh))[i] = h;
      ((unsigned short*)(ws + ol))[i] = l;
    }
  } else if (a == 1 || a == 2){
    if (i < 24576){
      float x = (a == 1 ? wihf : wihb)[i];
      unsigned short h = f2bf(x);
      unsigned short l = f2bf(x - bf2f(h));
      ((unsigned short*)(ws + (a == 1 ? OFF_WIHF_H : OFF_WIHB_H)))[i] = h;
      ((unsigned short*)(ws + (a == 1 ? OFF_WIHF_L : OFF_WIHB_L)))[i] = l;
    }
  } else if (a == 3 || a == 4){
    if (i < 12288){
      float x = (a == 3 ? whhf : whhb)[i];
      ((unsigned short*)(ws + (a == 3 ? OFF_WHHF_H : OFF_WHHB_H)))[i] = f2bf(x);
    }
  } else {
    if (i < 12288){
      float x = (a == 8 ? wihc : whhc)[i];
      unsigned short h = f2bf(x);
      unsigned short l = f2bf(x - bf2f(h));
      int oh = (a == 8 ? OFF_WIHC_H : OFF_WHHC_H);
      ((unsigned short*)(ws + oh))[i] = h;
      ((unsigned short*)(ws + oh + 6144))[i] = l;
    }
  }
}

// ---------------- K1: bidirectional 15-step GRU via bf16 MFMA ---------------
// (structure unchanged from R3/R5; this round: rcp-based activations)
__global__ __launch_bounds__(512, 2) void k_gru(const float* __restrict__ obs,
                                                float* __restrict__ ws){
  __shared__ float smem[18432];               // 72 KB -> 2 blocks/CU
  float* s_u2 = smem;                         // [j-node][196] rows g*64+l : 12544
  unsigned short* s_obs_h = (unsigned short*)(smem + 12544); // obs/h_enc hi [64][72]
  unsigned short* s_obs_l = s_obs_h + 4608;                  // lo [64][72]
  unsigned short* s_hbu   = (unsigned short*)(smem + 12544); // loop h: 2 x [64][88] (aliases)
  float* s_red = smem + 18176;                // 2 x [64][2] y-partials (parity)

  const int tid = threadIdx.x;
  const int nl  = tid & 63;
  const int grp = __builtin_amdgcn_readfirstlane(tid >> 6);
  const int dir = blockIdx.x >> 8;
  const int base = (blockIdx.x & 255) * 64;
  const int lw = grp >> 2;
  const int nw = grp & 3;
  const int q  = nl >> 4;
  const int i_c = nl & 15;
  const int node = 16*nw + i_c;

  // P0: stage obs as bf16 hi/lo [node][72]
  {
    float4 a = *(const float4*)&obs[base*64 + tid*8];
    float4 b = *(const float4*)&obs[base*64 + tid*8 + 4];
    int nn = tid >> 3, d0 = (tid & 7)*8;
    union { v8s v; unsigned short u[8]; } H, L;
    float xs[8] = {a.x,a.y,a.z,a.w,b.x,b.y,b.z,b.w};
    #pragma unroll
    for (int e = 0; e < 8; e++){
      H.u[e] = f2bf(xs[e]);
      L.u[e] = f2bf(xs[e] - bf2f(H.u[e]));
    }
    *(v8s*)&s_obs_h[nn*72 + d0] = H.v;
    *(v8s*)&s_obs_l[nn*72 + d0] = L.v;
  }
  __syncthreads();

  // P1: h_enc = relu(obs @ Wenc + b_enc) via MFMA
  const float* benc = ws + OFF_BENC;
  const unsigned short* wtH = (const unsigned short*)(ws + OFF_WENCT_H);
  const unsigned short* wtL = (const unsigned short*)(ws + OFF_WENCT_L);
  v4f dEnc[2];
  {
    v8s obH[2], obL[2];
    #pragma unroll
    for (int kc = 0; kc < 2; kc++){
      int ba = node*72 + kc*32 + q*8;
      obH[kc] = *(const v8s*)&s_obs_h[ba];
      obL[kc] = *(const v8s*)&s_obs_l[ba];
    }
    #pragma unroll
    for (int tt = 0; tt < 2; tt++){
      int lT = 2*lw + tt;
      float4 bi = *(const float4*)&benc[16*lT + 4*q];
      v4f d = (v4f){bi.x, bi.y, bi.z, bi.w};
      #pragma unroll
      for (int kc = 0; kc < 2; kc++){
        int aa = (16*lT + i_c)*64 + kc*32 + q*8;
        v8s aH = *(const v8s*)&wtH[aa];
        v8s aL = *(const v8s*)&wtL[aa];
        d = __builtin_amdgcn_mfma_f32_16x16x32_bf16(aH, obH[kc], d, 0,0,0);
        d = __builtin_amdgcn_mfma_f32_16x16x32_bf16(aH, obL[kc], d, 0,0,0);
        d = __builtin_amdgcn_mfma_f32_16x16x32_bf16(aL, obH[kc], d, 0,0,0);
      }
      dEnc[tt] = d;
    }
  }
  __syncthreads();
  #pragma unroll
  for (int tt = 0; tt < 2; tt++){
    int lT = 2*lw + tt;
    unsigned short hh[4], ll[4];
    #pragma unroll
    for (int r = 0; r < 4; r++){
      float v = fmaxf(dEnc[tt][r], 0.0f);
      hh[r] = f2bf(v);
      ll[r] = f2bf(v - bf2f(hh[r]));
    }
    int wa = node*72 + 16*lT + 4*q;
    *(uint2*)&s_obs_h[wa] = make_uint2((unsigned)hh[0] | ((unsigned)hh[1]<<16),
                                       (unsigned)hh[2] | ((unsigned)hh[3]<<16));
    *(uint2*)&s_obs_l[wa] = make_uint2((unsigned)ll[0] | ((unsigned)ll[1]<<16),
                                       (unsigned)ll[2] | ((unsigned)ll[3]<<16));
  }
  __syncthreads();

  const float* bih = ws + (dir ? OFF_BIHB : OFF_BIHF);
  const float* bhh = ws + (dir ? OFF_BHHB : OFF_BHHF);
  const unsigned short* wiH = (const unsigned short*)(ws + (dir ? OFF_WIHB_H : OFF_WIHF_H));
  const unsigned short* wiL = (const unsigned short*)(ws + (dir ? OFF_WIHB_L : OFF_WIHF_L));
  const unsigned short* whH = (const unsigned short*)(ws + (dir ? OFF_WHHB_H : OFF_WHHF_H));

  v8s hbH[2], hbL[2];
  #pragma unroll
  for (int kc = 0; kc < 2; kc++){
    int ba = node*72 + kc*32 + q*8;
    hbH[kc] = *(const v8s*)&s_obs_h[ba];
    hbL[kc] = *(const v8s*)&s_obs_l[ba];
  }

  // P2a: u2
  #pragma unroll
  for (int m = 0; m < 6; m++){
    int T = 6*lw + m;
    v4f d = (v4f){0.f,0.f,0.f,0.f};
    #pragma unroll
    for (int kc = 0; kc < 2; kc++){
      int aa = (16*T + i_c)*128 + 64 + kc*32 + q*8;
      v8s aH = *(const v8s*)&wiH[aa];
      v8s aL = *(const v8s*)&wiL[aa];
      d = __builtin_amdgcn_mfma_f32_16x16x32_bf16(aH, hbH[kc], d, 0,0,0);
      d = __builtin_amdgcn_mfma_f32_16x16x32_bf16(aH, hbL[kc], d, 0,0,0);
      d = __builtin_amdgcn_mfma_f32_16x16x32_bf16(aL, hbH[kc], d, 0,0,0);
    }
    *(v4f*)&s_u2[node*196 + 16*T + 4*q] = d;
  }

  // P2b: cb
  v4f cbr[2], cbz[2], cbn[2], bhn4[2];
  #pragma unroll
  for (int g = 0; g < 3; g++){
    #pragma unroll
    for (int t2 = 0; t2 < 2; t2++){
      int row0 = 64*g + 32*lw + 16*t2 + 4*q;
      float4 bi = *(const float4*)&bih[row0];
      v4f d;
      if (g < 2){
        float4 bh = *(const float4*)&bhh[row0];
        d = (v4f){bi.x+bh.x, bi.y+bh.y, bi.z+bh.z, bi.w+bh.w};
      } else {
        d = (v4f){bi.x, bi.y, bi.z, bi.w};
      }
      int T = (64*g + 32*lw + 16*t2) >> 4;
      #pragma unroll
      for (int kc = 0; kc < 2; kc++){
        int aa = (16*T + i_c)*128 + kc*32 + q*8;
        v8s aH = *(const v8s*)&wiH[aa];
        v8s aL = *(const v8s*)&wiL[aa];
        d = __builtin_amdgcn_mfma_f32_16x16x32_bf16(aH, hbH[kc], d, 0,0,0);
        d = __builtin_amdgcn_mfma_f32_16x16x32_bf16(aH, hbL[kc], d, 0,0,0);
        d = __builtin_amdgcn_mfma_f32_16x16x32_bf16(aL, hbH[kc], d, 0,0,0);
      }
      if (g == 0) cbr[t2] = d; else if (g == 1) cbz[t2] = d; else cbn[t2] = d;
    }
  }
  #pragma unroll
  for (int t2 = 0; t2 < 2; t2++){
    int row0 = 128 + 32*lw + 16*t2 + 4*q;
    float4 nh = *(const float4*)&bhh[row0];
    bhn4[t2] = (v4f){nh.x, nh.y, nh.z, nh.w};
  }

  // P2c: Whh A-frags
  v8s afr[2][2], afz[2][2], afn[2][2];
  #pragma unroll
  for (int t2 = 0; t2 < 2; t2++){
    #pragma unroll
    for (int kc = 0; kc < 2; kc++){
      #pragma unroll
      for (int g = 0; g < 3; g++){
        int row = g*64 + 32*lw + 16*t2 + i_c;
        v8s a = *(const v8s*)&whH[row*64 + kc*32 + q*8];
        if (g == 0) afr[t2][kc] = a; else if (g == 1) afz[t2][kc] = a; else afn[t2][kc] = a;
      }
    }
  }

  const float* whard = ws + OFF_WHARD + dir*128;
  float wh0[8], wh1[8];
  #pragma unroll
  for (int t2 = 0; t2 < 2; t2++){
    #pragma unroll
    for (int r = 0; r < 4; r++){
      int l = 32*lw + 16*t2 + 4*q + r;
      wh0[t2*4+r] = whard[l*2];
      wh1[t2*4+r] = whard[l*2+1];
    }
  }
  __syncthreads();

  // P3: 15-step recurrence
  float* yout = ws + (dir ? OFF_YB : OFF_YF);

  float hv[8];
  #pragma unroll
  for (int m = 0; m < 8; m++) hv[m] = 0.0f;

  for (int kk = 0; kk < 15; kk++){
    const int t  = dir ? (14 - kk) : kk;
    const int j  = t + (t >= i_c ? 1 : 0);
    const int jl = 16*nw + j;
    const int rb = kk & 1;
    const int wb = (kk + 1) & 1;

    v8s b0, b1;
    if (kk > 0){
      const unsigned short* rp = s_hbu + rb*5632 + node*88 + q*8;
      b0 = *(const v8s*)(rp);
      b1 = *(const v8s*)(rp + 32);
    }

    float a0p = 0.f, a1p = 0.f;
    #pragma unroll
    for (int t2 = 0; t2 < 2; t2++){
      int l0 = 32*lw + 16*t2 + 4*q;
      v4f dr = cbr[t2], dz = cbz[t2];
      v4f dn = (v4f){0.f,0.f,0.f,0.f};
      if (kk > 0){
        dr = __builtin_amdgcn_mfma_f32_16x16x32_bf16(afr[t2][0], b0, dr, 0,0,0);
        dr = __builtin_amdgcn_mfma_f32_16x16x32_bf16(afr[t2][1], b1, dr, 0,0,0);
        dz = __builtin_amdgcn_mfma_f32_16x16x32_bf16(afz[t2][0], b0, dz, 0,0,0);
        dz = __builtin_amdgcn_mfma_f32_16x16x32_bf16(afz[t2][1], b1, dz, 0,0,0);
        dn = __builtin_amdgcn_mfma_f32_16x16x32_bf16(afn[t2][0], b0, dn, 0,0,0);
        dn = __builtin_amdgcn_mfma_f32_16x16x32_bf16(afn[t2][1], b1, dn, 0,0,0);
      }
      v4f ur = *(const v4f*)&s_u2[jl*196 +       l0];
      v4f uz = *(const v4f*)&s_u2[jl*196 +  64 + l0];
      v4f un = *(const v4f*)&s_u2[jl*196 + 128 + l0];
      float hn[4];
      #pragma unroll
      for (int r = 0; r < 4; r++){
        float rg = sigf(dr[r] + ur[r]);
        float zg = sigf(dz[r] + uz[r]);
        float ng = tanhfast(cbn[t2][r] + un[r] + rg*(bhn4[t2][r] + dn[r]));
        float hnew = (1.0f - zg)*ng + zg*hv[t2*4+r];
        hv[t2*4+r] = hnew;
        hn[r] = hnew;
        a0p += hnew*wh0[t2*4+r];
        a1p += hnew*wh1[t2*4+r];
      }
      unsigned int p0 = (unsigned int)f2bf(hn[0]) | ((unsigned int)f2bf(hn[1]) << 16);
      unsigned int p1 = (unsigned int)f2bf(hn[2]) | ((unsigned int)f2bf(hn[3]) << 16);
      *(uint2*)(s_hbu + wb*5632 + node*88 + l0) = make_uint2(p0, p1);
    }

    a0p += __shfl_xor(a0p, 16); a0p += __shfl_xor(a0p, 32);
    a1p += __shfl_xor(a1p, 16); a1p += __shfl_xor(a1p, 32);
    float* sr = s_red + rb*128;
    if (lw == 0 && q == 0)
      *(float2*)&sr[node*2] = make_float2(a0p, a1p);
    __syncthreads();
    if (lw == 1 && q == 0){
      float2 pp = *(const float2*)&sr[node*2];
      *(float2*)&yout[((base + node)*15 + t)*2] = make_float2(a0p + pp.x, a1p + pp.y);
    }
  }
}

// ---------------- K2: qkv + gumbel + attention + final GRU cell -------------
// (structure unchanged from R5; rcp-based activations + rcp softmax denom)
__global__ __launch_bounds__(512, 1) void k_attn(const float* __restrict__ obs,
                                                 const float* __restrict__ hid,
                                                 const float* __restrict__ gum,
                                                 float* __restrict__ ws,
                                                 float* __restrict__ out){
  __shared__ float smem[14336];                        // 56 KB
  unsigned short* s_obs_h = (unsigned short*)smem;     // [64][72] obs/h_enc hi
  unsigned short* s_obs_l = s_obs_h + 4608;            // lo
  float* s_q  = smem;                                  // [64][68] fp32 (aliases, after frags)
  unsigned short* s_h0h = (unsigned short*)smem;       // h0 hi (aliases, late)
  unsigned short* s_h0l = s_h0h + 4608;
  float* s_k  = smem + 4608;                           // [64][65]
  unsigned short* s_xh = (unsigned short*)(smem + 4608); // x frags (alias s_k, late)
  unsigned short* s_xl = s_xh + 4608;
  float* s_v  = smem + 9216;                           // [64][65]
  float* s_co = smem + 13376;                          // [15][64]

  const int tid = threadIdx.x;
  const int nl  = tid & 63;
  const int grp = __builtin_amdgcn_readfirstlane(tid >> 6);
  const int base = blockIdx.x * 64;
  const int lw = grp >> 2;
  const int nw = grp & 3;
  const int q4 = nl >> 4;
  const int i_c = nl & 15;
  const int node = 16*nw + i_c;

  // P0: stage obs bf16 hi/lo [node][72]
  {
    float4 a = *(const float4*)&obs[base*64 + tid*8];
    float4 b = *(const float4*)&obs[base*64 + tid*8 + 4];
    int nn = tid >> 3, d0 = (tid & 7)*8;
    union { v8s v; unsigned short u[8]; } H, L;
    float xs[8] = {a.x,a.y,a.z,a.w,b.x,b.y,b.z,b.w};
    #pragma unroll
    for (int e = 0; e < 8; e++){
      H.u[e] = f2bf(xs[e]);
      L.u[e] = f2bf(xs[e] - bf2f(H.u[e]));
    }
    *(v8s*)&s_obs_h[nn*72 + d0] = H.v;
    *(v8s*)&s_obs_l[nn*72 + d0] = L.v;
  }
  __syncthreads();

  // P1: h_enc via MFMA
  const float* benc = ws + OFF_BENC;
  const unsigned short* wtH = (const unsigned short*)(ws + OFF_WENCT_H);
  const unsigned short* wtL = (const unsigned short*)(ws + OFF_WENCT_L);
  v4f dEnc[2];
  {
    v8s obH[2], obL[2];
    #pragma unroll
    for (int kc = 0; kc < 2; kc++){
      int ba = node*72 + kc*32 + q4*8;
      obH[kc] = *(const v8s*)&s_obs_h[ba];
      obL[kc] = *(const v8s*)&s_obs_l[ba];
    }
    #pragma unroll
    for (int tt = 0; tt < 2; tt++){
      int lT = 2*lw + tt;
      float4 bi = *(const float4*)&benc[16*lT + 4*q4];
      v4f d = (v4f){bi.x, bi.y, bi.z, bi.w};
      #pragma unroll
      for (int kc = 0; kc < 2; kc++){
        int aa = (16*lT + i_c)*64 + kc*32 + q4*8;
        v8s aH = *(const v8s*)&wtH[aa];
        v8s aL = *(const v8s*)&wtL[aa];
        d = __builtin_amdgcn_mfma_f32_16x16x32_bf16(aH, obH[kc], d, 0,0,0);
        d = __builtin_amdgcn_mfma_f32_16x16x32_bf16(aH, obL[kc], d, 0,0,0);
        d = __builtin_amdgcn_mfma_f32_16x16x32_bf16(aL, obH[kc], d, 0,0,0);
      }
      dEnc[tt] = d;
    }
  }
  __syncthreads();
  #pragma unroll
  for (int tt = 0; tt < 2; tt++){
    int lT = 2*lw + tt;
    unsigned short hh[4], ll[4];
    #pragma unroll
    for (int r = 0; r < 4; r++){
      float v = fmaxf(dEnc[tt][r], 0.0f);
      hh[r] = f2bf(v);
      ll[r] = f2bf(v - bf2f(hh[r]));
    }
    int wa = node*72 + 16*lT + 4*q4;
    *(uint2*)&s_obs_h[wa] = make_uint2((unsigned)hh[0] | ((unsigned)hh[1]<<16),
                                       (unsigned)hh[2] | ((unsigned)hh[3]<<16));
    *(uint2*)&s_obs_l[wa] = make_uint2((unsigned)ll[0] | ((unsigned)ll[1]<<16),
                                       (unsigned)ll[2] | ((unsigned)ll[3]<<16));
  }
  __syncthreads();

  // C: h_enc B-frags; q/k/v MFMA (registers only)
  v8s hbH[2], hbL[2];
  #pragma unroll
  for (int kc = 0; kc < 2; kc++){
    int ba = node*72 + kc*32 + q4*8;
    hbH[kc] = *(const v8s*)&s_obs_h[ba];
    hbL[kc] = *(const v8s*)&s_obs_l[ba];
  }
  const unsigned short* wqH = (const unsigned short*)(ws + OFF_WQT_H);
  const unsigned short* wqL = (const unsigned short*)(ws + OFF_WQT_L);
  const unsigned short* wkH = (const unsigned short*)(ws + OFF_WKT_H);
  const unsigned short* wkL = (const unsigned short*)(ws + OFF_WKT_L);
  const unsigned short* wvH = (const unsigned short*)(ws + OFF_WVT_H);
  const unsigned short* wvL = (const unsigned short*)(ws + OFF_WVT_L);
  const float* bv = ws + OFF_BV;
  v4f dq[2], dk[2], dv[2];
  #pragma unroll
  for (int a2 = 0; a2 < 2; a2++){
    int aT = 2*lw + a2;
    v4f q_ = (v4f){0.f,0.f,0.f,0.f};
    v4f k_ = (v4f){0.f,0.f,0.f,0.f};
    float4 b4 = *(const float4*)&bv[16*aT + 4*q4];
    v4f v_ = (v4f){b4.x, b4.y, b4.z, b4.w};
    #pragma unroll
    for (int kc = 0; kc < 2; kc++){
      int ai = (16*aT + i_c)*64 + kc*32 + q4*8;
      v8s aH = *(const v8s*)&wqH[ai]; v8s aL = *(const v8s*)&wqL[ai];
      q_ = __builtin_amdgcn_mfma_f32_16x16x32_bf16(aH, hbH[kc], q_, 0,0,0);
      q_ = __builtin_amdgcn_mfma_f32_16x16x32_bf16(aH, hbL[kc], q_, 0,0,0);
      q_ = __builtin_amdgcn_mfma_f32_16x16x32_bf16(aL, hbH[kc], q_, 0,0,0);
      aH = *(const v8s*)&wkH[ai]; aL = *(const v8s*)&wkL[ai];
      k_ = __builtin_amdgcn_mfma_f32_16x16x32_bf16(aH, hbH[kc], k_, 0,0,0);
      k_ = __builtin_amdgcn_mfma_f32_16x16x32_bf16(aH, hbL[kc], k_, 0,0,0);
      k_ = __builtin_amdgcn_mfma_f32_16x16x32_bf16(aL, hbH[kc], k_, 0,0,0);
      aH = *(const v8s*)&wvH[ai]; aL = *(const v8s*)&wvL[ai];
      v_ = __builtin_amdgcn_mfma_f32_16x16x32_bf16(aH, hbH[kc], v_, 0,0,0);
      v_ = __builtin_amdgcn_mfma_f32_16x16x32_bf16(aH, hbL[kc], v_, 0,0,0);
      v_ = __builtin_amdgcn_mfma_f32_16x16x32_bf16(aL, hbH[kc], v_, 0,0,0);
    }
    dq[a2] = q_; dk[a2] = k_; dv[a2] = v_;
  }
  __syncthreads();   // all s_obs frag reads done -> s_q (alias) writable

  // D: store q [node][68], k/v [a][65]
  #pragma unroll
  for (int a2 = 0; a2 < 2; a2++){
    int aT = 2*lw + a2;
    *(v4f*)&s_q[node*68 + 16*aT + 4*q4] = dq[a2];
    #pragma unroll
    for (int r = 0; r < 4; r++){
      s_k[(16*aT + 4*q4 + r)*65 + node] = dk[a2][r];
      s_v[(16*aT + 4*q4 + r)*65 + node] = fmaxf(dv[a2][r], 0.f);
    }
  }
  __syncthreads();

  // E: scores + softmax + gumbel coeffs.  Remap: n2 = node, asl = a-slice.
  const int n2  = tid >> 3;
  const int asl = tid & 7;
  const int ib2 = n2 & 15, jb2 = n2 & 48;
  float4 aq0 = *(const float4*)&s_q[n2*68 + asl*8];
  float4 aq1 = *(const float4*)&s_q[n2*68 + asl*8 + 4];
  float sc[15];
  #pragma unroll
  for (int t = 0; t < 15; t++){
    int jl = jb2 | (t + (t >= ib2 ? 1 : 0));
    const float* kp = s_k + (asl*8)*65 + jl;
    float s = aq0.x*kp[0]   + aq0.y*kp[65]  + aq0.z*kp[130] + aq0.w*kp[195]
            + aq1.x*kp[260] + aq1.y*kp[325] + aq1.z*kp[390] + aq1.w*kp[455];
    s += __shfl_xor(s, 1); s += __shfl_xor(s, 2); s += __shfl_xor(s, 4);
    sc[t] = s * 0.125f;
  }
  {
    float m = sc[0];
    #pragma unroll
    for (int t = 1; t < 15; t++) m = fmaxf(m, sc[t]);
    float den = 0.f;
    #pragma unroll
    for (int t = 0; t < 15; t++) den += __expf(sc[t]-m);
    float rden = rcpf(den);
    const float bh0 = ws[OFF_BHARD], bh1 = ws[OFF_BHARD+1];
    const float* yF = ws + OFF_YF; const float* yB = ws + OFF_YB;
    #pragma unroll
    for (int t = 0; t < 15; t++){
      if ((t & 7) == asl){
        int rowb = ((base + n2)*15 + t)*2;
        float y0 = yF[rowb]   + yB[rowb]   + bh0;
        float y1 = yF[rowb+1] + yB[rowb+1] + bh1;
        float2 u2 = *(const float2*)&gum[rowb];
        float g0 = -__logf(-__logf(u2.x + EPSG) + EPSG);
        float g1 = -__logf(-__logf(u2.y + EPSG) + EPSG);
        float w  = sigf(((y1+g1) - (y0+g0)) * (1.0f/TAU_));
        s_co[t*64 + n2] = __expf(sc[t]-m)*rden*w;
      }
    }
  }
  __syncthreads();

  // F: x = sum_t coeff * v  (8 a's per thread), write x bf16 frags; stage h0
  {
    float xa[8];
    #pragma unroll
    for (int il = 0; il < 8; il++) xa[il] = 0.f;
    #pragma unroll
    for (int t = 0; t < 15; t++){
      float c = s_co[t*64 + n2];
      int jl = jb2 | (t + (t >= ib2 ? 1 : 0));
      const float* vp = s_v + (asl*8)*65 + jl;
      xa[0] += c*vp[0];   xa[1] += c*vp[65];  xa[2] += c*vp[130]; xa[3] += c*vp[195];
      xa[4] += c*vp[260]; xa[5] += c*vp[325]; xa[6] += c*vp[390]; xa[7] += c*vp[455];
    }
    union { v8s v; unsigned short u[8]; } XH, XL;
    #pragma unroll
    for (int e = 0; e < 8; e++){
      XH.u[e] = f2bf(xa[e]);
      XL.u[e] = f2bf(xa[e] - bf2f(XH.u[e]));
    }
    *(v8s*)&s_xh[n2*72 + asl*8] = XH.v;
    *(v8s*)&s_xl[n2*72 + asl*8] = XL.v;
  }
  {
    float4 a = *(const float4*)&hid[base*64 + tid*8];
    float4 b = *(const float4*)&hid[base*64 + tid*8 + 4];
    int nn = tid >> 3, d0 = (tid & 7)*8;
    union { v8s v; unsigned short u[8]; } H, L;
    float xs[8] = {a.x,a.y,a.z,a.w,b.x,b.y,b.z,b.w};
    #pragma unroll
    for (int e = 0; e < 8; e++){
      H.u[e] = f2bf(xs[e]);
      L.u[e] = f2bf(xs[e] - bf2f(H.u[e]));
    }
    *(v8s*)&s_h0h[nn*72 + d0] = H.v;
    *(v8s*)&s_h0l[nn*72 + d0] = L.v;
  }
  __syncthreads();

  // G: final GRU cell via MFMA: gi = Wihc.x, gh = Whhc.h0
  v8s xbH[2], xbL[2], h0H[2], h0L[2];
  #pragma unroll
  for (int kc = 0; kc < 2; kc++){
    int ba = node*72 + kc*32 + q4*8;
    xbH[kc] = *(const v8s*)&s_xh[ba];  xbL[kc] = *(const v8s*)&s_xl[ba];
    h0H[kc] = *(const v8s*)&s_h0h[ba]; h0L[kc] = *(const v8s*)&s_h0l[ba];
  }
  const unsigned short* wiH = (const unsigned short*)(ws + OFF_WIHC_H);
  const unsigned short* wiL = (const unsigned short*)(ws + OFF_WIHC_L);
  const unsigned short* whH = (const unsigned short*)(ws + OFF_WHHC_H);
  const unsigned short* whL = (const unsigned short*)(ws + OFF_WHHC_L);
  const float* bihc = ws + OFF_BIHC; const float* bhhc = ws + OFF_BHHC;
  v4f gi[3][2], gh[3][2];
  #pragma unroll
  for (int g = 0; g < 3; g++){
    #pragma unroll
    for (int u2 = 0; u2 < 2; u2++){
      int u = 2*lw + u2;
      int row0 = g*64 + 16*u + 4*q4;
      float4 bi = *(const float4*)&bihc[row0];
      float4 bh = *(const float4*)&bhhc[row0];
      v4f di, dh;
      if (g < 2){
        di = (v4f){bi.x+bh.x, bi.y+bh.y, bi.z+bh.z, bi.w+bh.w};
        dh = (v4f){0.f,0.f,0.f,0.f};
      } else {
        di = (v4f){bi.x, bi.y, bi.z, bi.w};
        dh = (v4f){bh.x, bh.y, bh.z, bh.w};
      }
      #pragma unroll
      for (int kc = 0; kc < 2; kc++){
        int ai = (g*64 + 16*u + i_c)*64 + kc*32 + q4*8;
        v8s aH = *(const v8s*)&wiH[ai]; v8s aL = *(const v8s*)&wiL[ai];
        di = __builtin_amdgcn_mfma_f32_16x16x32_bf16(aH, xbH[kc], di, 0,0,0);
        di = __builtin_amdgcn_mfma_f32_16x16x32_bf16(aH, xbL[kc], di, 0,0,0);
        di = __builtin_amdgcn_mfma_f32_16x16x32_bf16(aL, xbH[kc], di, 0,0,0);
        aH = *(const v8s*)&whH[ai]; aL = *(const v8s*)&whL[ai];
        dh = __builtin_amdgcn_mfma_f32_16x16x32_bf16(aH, h0H[kc], dh, 0,0,0);
        dh = __builtin_amdgcn_mfma_f32_16x16x32_bf16(aH, h0L[kc], dh, 0,0,0);
        dh = __builtin_amdgcn_mfma_f32_16x16x32_bf16(aL, h0H[kc], dh, 0,0,0);
      }
      gi[g][u2] = di; gh[g][u2] = dh;
    }
  }
  #pragma unroll
  for (int u2 = 0; u2 < 2; u2++){
    int l0 = 16*(2*lw + u2) + 4*q4;
    float4 h04 = *(const float4*)&hid[(base+node)*64 + l0];
    float hh[4] = {h04.x, h04.y, h04.z, h04.w};
    float ho[4];
    #pragma unroll
    for (int r = 0; r < 4; r++){
      float rg = sigf(gi[0][u2][r] + gh[0][u2][r]);
      float zg = sigf(gi[1][u2][r] + gh[1][u2][r]);
      float ng = tanhfast(gi[2][u2][r] + rg*gh[2][u2][r]);
      ho[r] = (1.0f - zg)*ng + zg*hh[r];
    }
    *(float4*)&out[(base+node)*64 + l0] = make_float4(ho[0], ho[1], ho[2], ho[3]);
  }
}

extern "C" void kernel_launch(void* const* d_in, const int* in_sizes, int n_in,
                              void* d_out, int out_size, void* d_ws, size_t ws_size,
                              hipStream_t stream){
  if (ws_size < (size_t)WS_FLOATS * sizeof(float)) return;
  float* ws = (float*)d_ws;
  // f32 copies still needed; MFMA weights go through k_prep2 bf16 splits
  static const int offs[20] = {OFF_WENC, OFF_BENC, 0, 0, OFF_BIHF, OFF_BHHF,
      0, 0, OFF_BIHB, OFF_BHHB, OFF_WHARD, OFF_BHARD, 0, 0, 0,
      OFF_BV, 0, 0, OFF_BIHC, OFF_BHHC};
  Prep p;
  for (int i = 0; i < 20; i++){
    p.s[i] = (const float*)d_in[3 + i];
    p.n[i] = in_sizes[3 + i];
    p.o[i] = offs[i];
  }
  // zero out f32 copies replaced by bf16 splits:
  p.n[2] = 0; p.n[3] = 0; p.n[6] = 0; p.n[7] = 0;      // Wih_f/Whh_f/Wih_b/Whh_b
  p.n[12] = 0; p.n[13] = 0; p.n[14] = 0;               // Wq/Wk/Wv
  p.n[16] = 0; p.n[17] = 0;                            // Wih_c/Whh_c
  hipLaunchKernelGGL(k_prep, dim3(96, 20), dim3(256), 0, stream, p, ws);
  hipLaunchKernelGGL(k_prep2, dim3(96, 10), dim3(256), 0, stream,
                     (const float*)d_in[3], (const float*)d_in[5], (const float*)d_in[9],
                     (const float*)d_in[6], (const float*)d_in[10],
                     (const float*)d_in[15], (const float*)d_in[16], (const float*)d_in[17],
                     (const float*)d_in[19], (const float*)d_in[20], ws);
  hipLaunchKernelGGL(k_gru,  dim3(512),    dim3(512), 0, stream,
                     (const float*)d_in[0], ws);
  hipLaunchKernelGGL(k_attn, dim3(256),    dim3(512), 0, stream,
                     (const float*)d_in[0], (const float*)d_in[1],
                     (const float*)d_in[2], ws, (float*)d_out);
}